// Round 2
// baseline (720.259 us; speedup 1.0000x reference)
//
#include <hip/hip_runtime.h>
#include <hip/hip_bf16.h>

typedef unsigned short ushort_t;
typedef __attribute__((ext_vector_type(8))) short short8;
typedef __attribute__((ext_vector_type(4))) float float4v;

__device__ __forceinline__ float bfu_lo(unsigned u) {
    return __uint_as_float(u << 16);
}
__device__ __forceinline__ float bfu_hi(unsigned u) {
    return __uint_as_float(u & 0xffff0000u);
}
__device__ __forceinline__ ushort_t f2bf(float f) {
    __hip_bfloat16 h = __float2bfloat16(f);
    return *reinterpret_cast<ushort_t*>(&h);
}

// Wall layout per layer: 30 col-tiles (466 cols used), tile = 1024 ushorts:
//   idx = ct*1024 + kch*512 + lane*8 + j
// cols: 0..127 q | 128..255 k | 256..383 v | 384..447 skip | 448..465 qc

// ---------------- fused setup ----------------

__global__ __launch_bounds__(256) void setup_kernel(
    const float* __restrict__ x, const float* __restrict__ node_W,
    const float* __restrict__ node_b,
    const float* __restrict__ edge_W, const float* __restrict__ edge_b,
    const float* __restrict__ We, const float* __restrict__ be,
    const float* __restrict__ Wq, const float* __restrict__ bq,
    const float* __restrict__ Wk, const float* __restrict__ bk,
    const float* __restrict__ Wv, const float* __restrict__ bv,
    const float* __restrict__ Wskip, const float* __restrict__ bskip,
    float* __restrict__ h, ushort_t* __restrict__ h_bf,
    int* __restrict__ counts,
    float* __restrict__ Wc, float* __restrict__ bcb,
    ushort_t* __restrict__ Wall_arr, float* __restrict__ Wall_bias,
    int O0, int O1, int O2, int N) {
    int b = blockIdx.x, t = threadIdx.x;
    if (b < O0) {
        int idx = b * 256 + t;
        if (idx < N * 64) {
            int n = idx >> 6, c = idx & 63;
            float acc = node_b[c];
#pragma unroll
            for (int j = 0; j < 16; ++j) acc += x[n * 16 + j] * node_W[j * 64 + c];
            h[idx] = acc;
            h_bf[idx] = f2bf(acc);
        }
    } else if (b < O1) {
        int i = (b - O0) * 256 + t;
        if (i < N) counts[i] = 0;
    } else if (b < O2) {
        int tid = (b - O1) * 256 + t;
        if (tid < 2048) {
            int l = tid >> 10, d = (tid >> 7) & 7, j = tid & 127;
            float s = 0.f;
            for (int m = 0; m < 64; ++m) s += edge_W[d * 64 + m] * We[l * 8192 + m * 128 + j];
            Wc[l * 1024 + d * 128 + j] = s;
        } else if (tid < 2048 + 256) {
            int u = tid - 2048;
            int l = u >> 7, j = u & 127;
            float s = be[l * 128 + j];
            for (int m = 0; m < 64; ++m) s += edge_b[m] * We[l * 8192 + m * 128 + j];
            bcb[l * 128 + j] = s;
        }
    } else {
        int tid = (b - O2) * 256 + t;
        if (tid < 2 * 28672) {
            int l = tid / 28672, u = tid % 28672;
            int j = u & 7, ln = (u >> 3) & 63, kch = (u >> 9) & 1, ct = u >> 10;
            int nn = ln & 15, quad = ln >> 4;
            int k = kch * 32 + quad * 8 + j;
            int col = ct * 16 + nn;
            float v;
            if (col < 128)      v = Wq[l * 8192 + k * 128 + col];
            else if (col < 256) v = Wk[l * 8192 + k * 128 + col - 128];
            else if (col < 384) v = Wv[l * 8192 + k * 128 + col - 256];
            else                v = Wskip[l * 4096 + k * 64 + col - 384];
            Wall_arr[(size_t)l * 32768 + ct * 1024 + kch * 512 + ln * 8 + j] = f2bf(v);
        } else if (tid < 2 * 28672 + 2 * 448) {
            int u = tid - 2 * 28672;
            int l = u / 448, col = u % 448;
            float v;
            if (col < 128)      v = bq[l * 128 + col];
            else if (col < 256) v = bk[l * 128 + col - 128];
            else if (col < 384) v = bv[l * 128 + col - 256];
            else                v = bskip[l * 64 + col - 384];
            Wall_bias[l * 512 + col] = v;
        }
    }
}

// combine2: qc composed weights into Wall fragments
__global__ void combine2_kernel(const float* __restrict__ Wq, const float* __restrict__ bq,
                                const float* __restrict__ Wc, const float* __restrict__ bcb,
                                ushort_t* __restrict__ Wall_arr, float* __restrict__ Wall_bias) {
    int tid = blockIdx.x * 256 + threadIdx.x;
    if (tid < 2304) {
        int l = tid / 1152, u = tid % 1152, k = u / 18, j = u % 18;
        float s = 0.f;
        if (j < 16) {
            int hh = j >> 3, d = j & 7;
            for (int c = 0; c < 64; ++c)
                s += Wq[l * 8192 + k * 128 + hh * 64 + c] * Wc[l * 1024 + d * 128 + hh * 64 + c];
        } else {
            int hh = j - 16;
            for (int c = 0; c < 64; ++c)
                s += Wq[l * 8192 + k * 128 + hh * 64 + c] * bcb[l * 128 + hh * 64 + c];
        }
        s *= 0.125f;
        int col = 448 + j;
        int ct = col >> 4, nn = col & 15;
        int kch = k >> 5, quad = (k >> 3) & 3, jj = k & 7;
        int ln = quad * 16 + nn;
        Wall_arr[(size_t)l * 32768 + ct * 1024 + kch * 512 + ln * 8 + jj] = f2bf(s);
    } else if (tid < 2304 + 36) {
        int u = tid - 2304;
        int l = u / 18, j = u % 18;
        float s = 0.f;
        if (j < 16) {
            int hh = j >> 3, d = j & 7;
            for (int c = 0; c < 64; ++c)
                s += bq[l * 128 + hh * 64 + c] * Wc[l * 1024 + d * 128 + hh * 64 + c];
        } else {
            int hh = j - 16;
            for (int c = 0; c < 64; ++c)
                s += bq[l * 128 + hh * 64 + c] * bcb[l * 128 + hh * 64 + c];
        }
        Wall_bias[l * 512 + 448 + j] = 0.125f * s;
    }
}

// ---------------- CSR build + degree-sort ----------------

__global__ void csr_count_kernel(const int* __restrict__ dst, int* __restrict__ counts,
                                 int* __restrict__ hist, int E) {
    if (blockIdx.x == 0 && threadIdx.x < 64) hist[threadIdx.x] = 0;
    int e = blockIdx.x * 256 + threadIdx.x;
    if (e < E) atomicAdd(&counts[dst[e]], 1);
}

__global__ void deg_hist_kernel(const int* __restrict__ counts, int* __restrict__ hist, int N) {
    int n = blockIdx.x * 256 + threadIdx.x;
    if (n < N) {
        int b = 63 - min(counts[n], 63);   // descending degree order
        atomicAdd(&hist[b], 1);
    }
}

__global__ void deg_scan_kernel(int* __restrict__ hist) {
    int t = threadIdx.x;   // 64 threads, 1 wave
    int v = hist[t];
    int s = v;
#pragma unroll
    for (int d = 1; d < 64; d <<= 1) {
        int x = __shfl_up(s, d);
        if (t >= d) s += x;
    }
    hist[t] = s - v;       // exclusive prefix
}

__global__ void perm_scatter_kernel(const int* __restrict__ counts, int* __restrict__ hist,
                                    int* __restrict__ perm, int N) {
    int n = blockIdx.x * 256 + threadIdx.x;
    if (n < N) {
        int b = 63 - min(counts[n], 63);
        int pos = atomicAdd(&hist[b], 1);
        perm[pos] = n;
    }
}

__global__ void scan1_kernel(const int* __restrict__ counts, int* __restrict__ rowptr,
                             int* __restrict__ bsums, int N) {
    __shared__ int s[256];
    int t = threadIdx.x, i = blockIdx.x * 256 + t;
    int v = (i < N) ? counts[i] : 0;
    s[t] = v;
    __syncthreads();
    for (int d = 1; d < 256; d <<= 1) {
        int x = (t >= d) ? s[t - d] : 0;
        __syncthreads();
        s[t] += x;
        __syncthreads();
    }
    if (i < N) rowptr[i] = s[t] - v;
    if (t == 255) bsums[blockIdx.x] = s[255];
}

// scan3 with scan2 folded in
__global__ void scan3_kernel(int* __restrict__ rowptr, const int* __restrict__ bsums,
                             int* __restrict__ cursor, int N, int E, int nb) {
    __shared__ int sh[256];
    int t = threadIdx.x;
    int v = (t < nb) ? bsums[t] : 0;
    sh[t] = v;
    __syncthreads();
    for (int d = 1; d < 256; d <<= 1) {
        int x = (t >= d) ? sh[t - d] : 0;
        __syncthreads();
        sh[t] += x;
        __syncthreads();
    }
    int blk = blockIdx.x;
    int offv = (blk == 0) ? 0 : sh[blk - 1];
    int i = blk * 256 + t;
    if (i < N) {
        int r = rowptr[i] + offv;
        rowptr[i] = r;
        cursor[i] = r;
    }
    if (i == 0) rowptr[N] = E;
}

__global__ void csr_fill_kernel(const int* __restrict__ dst, const int* __restrict__ src,
                                const float* __restrict__ edge_attr, int* __restrict__ cursor,
                                int* __restrict__ csr_src, float* __restrict__ ea_perm, int E) {
    int e = blockIdx.x * 256 + threadIdx.x;
    if (e < E) {
        int pos = atomicAdd(&cursor[dst[e]], 1);
        csr_src[pos] = src[e] * 768 + 256;
        float4 a0 = *(const float4*)(edge_attr + (size_t)e * 8);
        float4 a1 = *(const float4*)(edge_attr + (size_t)e * 8 + 4);
        *(float4*)(ea_perm + (size_t)pos * 8) = a0;
        *(float4*)(ea_perm + (size_t)pos * 8 + 4) = a1;
    }
}

// ---------------- per-layer MFMA GEMM: [32 x 64] @ [64 x 466] (from global h_bf) ----

__global__ __launch_bounds__(256) void qkv_mfma_kernel(
    const ushort_t* __restrict__ h_bf,
    const ushort_t* __restrict__ Wall_arr, const float* __restrict__ Wall_bias,
    ushort_t* __restrict__ qkv, float* __restrict__ outbuf, float* __restrict__ qcbuf, int N) {
    int wave = threadIdx.x >> 6, lane = threadIdx.x & 63;
    int quad = lane >> 4, nn = lane & 15;
    int n0 = blockIdx.x * 32;
    int nodeA = n0 + nn;       if (nodeA >= N) nodeA = N - 1;
    int nodeB = n0 + 16 + nn;  if (nodeB >= N) nodeB = N - 1;
    const ushort_t* apA = h_bf + (size_t)nodeA * 64 + quad * 8;
    const ushort_t* apB = h_bf + (size_t)nodeB * 64 + quad * 8;
    short8 aA0 = *(const short8*)apA;
    short8 aA1 = *(const short8*)(apA + 32);
    short8 aB0 = *(const short8*)apB;
    short8 aB1 = *(const short8*)(apB + 32);
    int ct_start = (wave < 2) ? wave * 8 : (16 + (wave - 2) * 7);
    int ct_cnt = (wave < 2) ? 8 : 7;
    for (int i = 0; i < ct_cnt; ++i) {
        int ct = ct_start + i;
        const ushort_t* bp = Wall_arr + (size_t)ct * 1024 + lane * 8;
        short8 b0 = *(const short8*)bp;
        short8 b1 = *(const short8*)(bp + 512);
        float4v cA = {0.f, 0.f, 0.f, 0.f};
        float4v cB = {0.f, 0.f, 0.f, 0.f};
        cA = __builtin_amdgcn_mfma_f32_16x16x32_bf16(aA0, b0, cA, 0, 0, 0);
        cA = __builtin_amdgcn_mfma_f32_16x16x32_bf16(aA1, b1, cA, 0, 0, 0);
        cB = __builtin_amdgcn_mfma_f32_16x16x32_bf16(aB0, b0, cB, 0, 0, 0);
        cB = __builtin_amdgcn_mfma_f32_16x16x32_bf16(aB1, b1, cB, 0, 0, 0);
        int col = ct * 16 + nn;
        float bias = Wall_bias[col];
#pragma unroll
        for (int g = 0; g < 2; ++g) {
            float4v c = (g == 0) ? cA : cB;
            int nbase = n0 + g * 16 + quad * 4;
            if (col < 384) {
                int cm;
                if (col < 128) cm = col;
                else if (col < 256) { int cc = col - 128; cm = 128 + ((cc >> 1) << 2) + (cc & 1); }
                else { int cc = col - 256; cm = 128 + ((cc >> 1) << 2) + 2 + (cc & 1); }
                ushort_t* qp = qkv + (size_t)nbase * 384 + cm;
#pragma unroll
                for (int r = 0; r < 4; ++r)
                    if (nbase + r < N) qp[(size_t)r * 384] = f2bf(c[r] + bias);
            } else if (col < 448) {
                float* op = outbuf + (size_t)nbase * 64 + (col - 448 + 64);
#pragma unroll
                for (int r = 0; r < 4; ++r)
                    if (nbase + r < N) op[(size_t)r * 64] = c[r] + bias;
            } else if (col < 466) {
                float* qp2 = qcbuf + (size_t)nbase * 20 + (col - 448);
#pragma unroll
                for (int r = 0; r < 4; ++r)
                    if (nbase + r < N) qp2[(size_t)r * 20] = c[r] + bias;
            }
        }
    }
}

// ---------------- fused BN-apply(l) + qkv-MFMA(l+1): 32 nodes/block ----------------

__global__ __launch_bounds__(256) void bnqkv_kernel(
    const float* __restrict__ outbuf_in, const float* __restrict__ bnsums,
    const float* __restrict__ gamma, const float* __restrict__ beta,
    float* __restrict__ h,
    const ushort_t* __restrict__ Wall_arr, const float* __restrict__ Wall_bias,
    ushort_t* __restrict__ qkv, float* __restrict__ outbuf, float* __restrict__ qcbuf, int N) {
    __shared__ ushort_t hb[32 * 64];
    __shared__ float ss_scale[64], ss_shift[64];
    int t = threadIdx.x;
    if (t < 64) {
        float invN = 1.f / (float)N;
        float mean = bnsums[t] * invN;
        float var = bnsums[64 + t] * invN - mean * mean;
        float sc = gamma[t] * rsqrtf(var + 1e-5f);
        ss_scale[t] = sc;
        ss_shift[t] = beta[t] - mean * sc;
    }
    __syncthreads();
    int n0 = blockIdx.x * 32;
    int c = t & 63;
    float sc = ss_scale[c], sh = ss_shift[c];
#pragma unroll
    for (int i = 0; i < 8; ++i) {
        int li = t + i * 256;
        int gidx = n0 * 64 + li;
        float hn = 0.f;
        if (gidx < N * 64) {
            float o = outbuf_in[gidx] * sc + sh;
            o = (o > 0.f) ? o : 0.01f * o;
            hn = h[gidx] + o;
            h[gidx] = hn;
        }
        hb[li] = f2bf(hn);
    }
    __syncthreads();
    int wave = t >> 6, lane = t & 63;
    int quad = lane >> 4, nn = lane & 15;
    const ushort_t* apA = hb + nn * 64 + quad * 8;
    const ushort_t* apB = hb + (16 + nn) * 64 + quad * 8;
    short8 aA0 = *(const short8*)apA;
    short8 aA1 = *(const short8*)(apA + 32);
    short8 aB0 = *(const short8*)apB;
    short8 aB1 = *(const short8*)(apB + 32);
    int ct_start = (wave < 2) ? wave * 8 : (16 + (wave - 2) * 7);
    int ct_cnt = (wave < 2) ? 8 : 7;
    for (int i = 0; i < ct_cnt; ++i) {
        int ct = ct_start + i;
        const ushort_t* bp = Wall_arr + (size_t)ct * 1024 + lane * 8;
        short8 b0 = *(const short8*)bp;
        short8 b1 = *(const short8*)(bp + 512);
        float4v cA = {0.f, 0.f, 0.f, 0.f};
        float4v cB = {0.f, 0.f, 0.f, 0.f};
        cA = __builtin_amdgcn_mfma_f32_16x16x32_bf16(aA0, b0, cA, 0, 0, 0);
        cA = __builtin_amdgcn_mfma_f32_16x16x32_bf16(aA1, b1, cA, 0, 0, 0);
        cB = __builtin_amdgcn_mfma_f32_16x16x32_bf16(aB0, b0, cB, 0, 0, 0);
        cB = __builtin_amdgcn_mfma_f32_16x16x32_bf16(aB1, b1, cB, 0, 0, 0);
        int col = ct * 16 + nn;
        float bias = Wall_bias[col];
#pragma unroll
        for (int g = 0; g < 2; ++g) {
            float4v cc2 = (g == 0) ? cA : cB;
            int nbase = n0 + g * 16 + quad * 4;
            if (col < 384) {
                int cm;
                if (col < 128) cm = col;
                else if (col < 256) { int cv = col - 128; cm = 128 + ((cv >> 1) << 2) + (cv & 1); }
                else { int cv = col - 256; cm = 128 + ((cv >> 1) << 2) + 2 + (cv & 1); }
                ushort_t* qp = qkv + (size_t)nbase * 384 + cm;
#pragma unroll
                for (int r = 0; r < 4; ++r)
                    if (nbase + r < N) qp[(size_t)r * 384] = f2bf(cc2[r] + bias);
            } else if (col < 448) {
                float* op = outbuf + (size_t)nbase * 64 + (col - 448 + 64);
#pragma unroll
                for (int r = 0; r < 4; ++r)
                    if (nbase + r < N) op[(size_t)r * 64] = cc2[r] + bias;
            } else if (col < 466) {
                float* qp2 = qcbuf + (size_t)nbase * 20 + (col - 448);
#pragma unroll
                for (int r = 0; r < 4; ++r)
                    if (nbase + r < N) qp2[(size_t)r * 20] = cc2[r] + bias;
            }
        }
    }
}

// ---------------- attention: 16-lane node groups, degree-sorted, 2 edges/iter ------
// lane l16 in [0,16): holds channels 8*l16 .. 8*l16+7 (l16<8 -> head 0, else head 1).
// Nodes assigned via perm[] (descending degree) so the 4 groups of a wave have
// near-equal degree (wdeg ~= deg) and long blocks launch first (LPT).

__global__ __launch_bounds__(256) void attn_kernel(
    const ushort_t* __restrict__ qkv, const float* __restrict__ qcbuf,
    const int* __restrict__ csr_src, const float* __restrict__ ea_perm,
    const int* __restrict__ rowptr, const int* __restrict__ perm,
    const float* __restrict__ Wc, const float* __restrict__ bcb,
    float* __restrict__ outbuf, float* __restrict__ part, int N) {
    __shared__ float Wc_s[1024];
    __shared__ float bc_s[128];
    __shared__ float stat[4][4][2][64];   // [wid][grp][sa|sq][chan]
    int t = threadIdx.x;
    for (int i = t; i < 1024; i += 256) Wc_s[i] = Wc[i];
    if (t < 128) bc_s[t] = bcb[t];
    {
        float* sf = &stat[0][0][0][0];
        for (int i = t; i < 2048; i += 256) sf[i] = 0.f;
    }
    __syncthreads();
    int lane = t & 63, wid = t >> 6;
    int grp = lane >> 4, l16 = lane & 15;
    int head = l16 >> 3, l8 = l16 & 7;
    const char* qkvb = (const char*)qkv;

    int slot = blockIdx.x * 16 + wid * 4 + grp;
    bool active = (slot < N);
    int nn = perm[active ? slot : (N - 1)];
    int start = rowptr[nn];
    int deg = active ? (rowptr[nn + 1] - start) : 0;
    int wdeg = deg;
    wdeg = max(wdeg, __shfl_xor(wdeg, 16));
    wdeg = max(wdeg, __shfl_xor(wdeg, 32));

    float lsum = 0.f;
    float vacc[8] = {0.f, 0.f, 0.f, 0.f, 0.f, 0.f, 0.f, 0.f};
    float se[8]   = {0.f, 0.f, 0.f, 0.f, 0.f, 0.f, 0.f, 0.f};

    if (wdeg > 0) {
        // q fragment: 8 channels per lane, packed bf16 pairs
        uint4 qr = *(const uint4*)(qkvb + (size_t)nn * 768 + 16 * l16);
        float qf0 = bfu_lo(qr.x), qf1 = bfu_hi(qr.x);
        float qf2 = bfu_lo(qr.y), qf3 = bfu_hi(qr.y);
        float qf4 = bfu_lo(qr.z), qf5 = bfu_hi(qr.z);
        float qf6 = bfu_lo(qr.w), qf7 = bfu_hi(qr.w);
        const float* qcp = qcbuf + (size_t)nn * 20;
        float4 qcA = *(const float4*)(qcp + head * 8);
        float4 qcB = *(const float4*)(qcp + head * 8 + 4);
        float qb = qcp[16 + head];

        bool dpos = (deg > 0);
        int dclamp = dpos ? (deg - 1) : 0;

        // 16-edge offset window held across the group's lanes
        int offL = csr_src[dpos ? (start + min(l16, dclamp)) : 0];

        int i1 = min(1, wdeg - 1);
        int o0 = __shfl(offL, grp * 16);
        int o1 = __shfl(offL, grp * 16 + i1);
        uint4 ca0 = *(const uint4*)(qkvb + (size_t)(unsigned)o0 + 32 * l16);
        uint4 cb0 = *(const uint4*)(qkvb + (size_t)(unsigned)o0 + 32 * l16 + 16);
        uint4 ca1 = *(const uint4*)(qkvb + (size_t)(unsigned)o1 + 32 * l16);
        uint4 cb1 = *(const uint4*)(qkvb + (size_t)(unsigned)o1 + 32 * l16 + 16);
        int g0 = dpos ? start : 0;
        int g1 = dpos ? (start + min(i1, dclamp)) : 0;
        float4 e00 = *(const float4*)(ea_perm + (size_t)g0 * 8);
        float4 e01 = *(const float4*)(ea_perm + (size_t)g0 * 8 + 4);
        float4 e10 = *(const float4*)(ea_perm + (size_t)g1 * 8);
        float4 e11 = *(const float4*)(ea_perm + (size_t)g1 * 8 + 4);

        for (int it = 0; it < wdeg; it += 2) {
            int p0 = it + 2;
            if ((p0 & 15) == 0 && p0 < wdeg)
                offL = csr_src[dpos ? (start + min(p0 + l16, dclamp)) : 0];
            int q0 = min(p0, wdeg - 1);
            int q1 = min(p0 + 1, wdeg - 1);
            int on0 = __shfl(offL, grp * 16 + (q0 & 15));
            int on1 = __shfl(offL, grp * 16 + (q1 & 15));
            uint4 na0 = *(const uint4*)(qkvb + (size_t)(unsigned)on0 + 32 * l16);
            uint4 nb0 = *(const uint4*)(qkvb + (size_t)(unsigned)on0 + 32 * l16 + 16);
            uint4 na1 = *(const uint4*)(qkvb + (size_t)(unsigned)on1 + 32 * l16);
            uint4 nb1 = *(const uint4*)(qkvb + (size_t)(unsigned)on1 + 32 * l16 + 16);
            int gn0 = dpos ? (start + min(q0, dclamp)) : 0;
            int gn1 = dpos ? (start + min(q1, dclamp)) : 0;
            float4 f00 = *(const float4*)(ea_perm + (size_t)gn0 * 8);
            float4 f01 = *(const float4*)(ea_perm + (size_t)gn0 * 8 + 4);
            float4 f10 = *(const float4*)(ea_perm + (size_t)gn1 * 8);
            float4 f11 = *(const float4*)(ea_perm + (size_t)gn1 * 8 + 4);

            float dt0 = qf0 * bfu_lo(ca0.x) + qf1 * bfu_hi(ca0.x)
                      + qf2 * bfu_lo(ca0.z) + qf3 * bfu_hi(ca0.z)
                      + qf4 * bfu_lo(cb0.x) + qf5 * bfu_hi(cb0.x)
                      + qf6 * bfu_lo(cb0.z) + qf7 * bfu_hi(cb0.z);
            float dt1 = qf0 * bfu_lo(ca1.x) + qf1 * bfu_hi(ca1.x)
                      + qf2 * bfu_lo(ca1.z) + qf3 * bfu_hi(ca1.z)
                      + qf4 * bfu_lo(cb1.x) + qf5 * bfu_hi(cb1.x)
                      + qf6 * bfu_lo(cb1.z) + qf7 * bfu_hi(cb1.z);
            dt0 += __shfl_xor(dt0, 1); dt1 += __shfl_xor(dt1, 1);
            dt0 += __shfl_xor(dt0, 2); dt1 += __shfl_xor(dt1, 2);
            dt0 += __shfl_xor(dt0, 4); dt1 += __shfl_xor(dt1, 4);
            float s00 = dt0 * 0.125f
                      + qcA.x * e00.x + qcA.y * e00.y + qcA.z * e00.z + qcA.w * e00.w
                      + qcB.x * e01.x + qcB.y * e01.y + qcB.z * e01.z + qcB.w * e01.w
                      + qb;
            float s01 = dt1 * 0.125f
                      + qcA.x * e10.x + qcA.y * e10.y + qcA.z * e10.z + qcA.w * e10.w
                      + qcB.x * e11.x + qcB.y * e11.y + qcB.z * e11.z + qcB.w * e11.w
                      + qb;
            float p0v = (it < deg) ? __expf(fmaxf(s00, -60.f)) : 0.f;
            float p1v = (it + 1 < deg) ? __expf(fmaxf(s01, -60.f)) : 0.f;
            lsum += p0v + p1v;
            vacc[0] += p0v * bfu_lo(ca0.y) + p1v * bfu_lo(ca1.y);
            vacc[1] += p0v * bfu_hi(ca0.y) + p1v * bfu_hi(ca1.y);
            vacc[2] += p0v * bfu_lo(ca0.w) + p1v * bfu_lo(ca1.w);
            vacc[3] += p0v * bfu_hi(ca0.w) + p1v * bfu_hi(ca1.w);
            vacc[4] += p0v * bfu_lo(cb0.y) + p1v * bfu_lo(cb1.y);
            vacc[5] += p0v * bfu_hi(cb0.y) + p1v * bfu_hi(cb1.y);
            vacc[6] += p0v * bfu_lo(cb0.w) + p1v * bfu_lo(cb1.w);
            vacc[7] += p0v * bfu_hi(cb0.w) + p1v * bfu_hi(cb1.w);
            se[0] += p0v * e00.x + p1v * e10.x;
            se[1] += p0v * e00.y + p1v * e10.y;
            se[2] += p0v * e00.z + p1v * e10.z;
            se[3] += p0v * e00.w + p1v * e10.w;
            se[4] += p0v * e01.x + p1v * e11.x;
            se[5] += p0v * e01.y + p1v * e11.y;
            se[6] += p0v * e01.z + p1v * e11.z;
            se[7] += p0v * e01.w + p1v * e11.w;
            ca0 = na0; cb0 = nb0; ca1 = na1; cb1 = nb1;
            e00 = f00; e01 = f01; e10 = f10; e11 = f11;
        }
    }

    if (active) {
        float inv = (deg > 0) ? (1.f / lsum) : 0.f;
        int jb = head * 64 + 8 * l8;
        float outv[8];
#pragma unroll
        for (int k2 = 0; k2 < 8; ++k2) {
            int j = jb + k2;
            float wv = lsum * bc_s[j];
#pragma unroll
            for (int m = 0; m < 8; ++m) wv += se[m] * Wc_s[m * 128 + j];
            float ox = (vacc[k2] + wv) * inv;
            float po = __shfl_xor(ox, 8);   // head exchange within group
            outv[k2] = 0.5f * (ox + po);
        }
        if (head == 0) {
            float* op = outbuf + (size_t)nn * 64 + 8 * l8;
            float4 c0 = *(const float4*)op;
            float4 c1 = *(const float4*)(op + 4);
            float fr[8];
            fr[0] = c0.x + outv[0]; fr[1] = c0.y + outv[1];
            fr[2] = c0.z + outv[2]; fr[3] = c0.w + outv[3];
            fr[4] = c1.x + outv[4]; fr[5] = c1.y + outv[5];
            fr[6] = c1.z + outv[6]; fr[7] = c1.w + outv[7];
            if (deg > 0) {
                *(float4*)op = make_float4(fr[0], fr[1], fr[2], fr[3]);
                *(float4*)(op + 4) = make_float4(fr[4], fr[5], fr[6], fr[7]);
            }
            float* sa = &stat[wid][grp][0][8 * l8];
            float* sq = &stat[wid][grp][1][8 * l8];
#pragma unroll
            for (int k2 = 0; k2 < 8; ++k2) {
                sa[k2] += fr[k2];
                sq[k2] += fr[k2] * fr[k2];
            }
        }
    }
    __syncthreads();
    if (t < 128) {
        int c = t & 63, qq = t >> 6;
        float s = 0.f;
#pragma unroll
        for (int w2 = 0; w2 < 4; ++w2)
#pragma unroll
            for (int g2 = 0; g2 < 4; ++g2) s += stat[w2][g2][qq][c];
        part[(size_t)blockIdx.x * 128 + t] = s;
    }
}

// ---------------- BN reduce + final-layer apply w/ gate ----------------

__global__ __launch_bounds__(256) void bnreduce_kernel(const float* __restrict__ part,
                                                       float* __restrict__ bnsums, int nb) {
    int s = blockIdx.x;  // 0..127
    int t = threadIdx.x;
    float a = 0.f;
    for (int b = t; b < nb; b += 256) a += part[(size_t)b * 128 + s];
    __shared__ float sh[256];
    sh[t] = a;
    __syncthreads();
    for (int d = 128; d; d >>= 1) {
        if (t < d) sh[t] += sh[t + d];
        __syncthreads();
    }
    if (t == 0) bnsums[s] = sh[0];
}

__global__ __launch_bounds__(256) void bnapply_kernel(
    const float* __restrict__ outbuf, const float* __restrict__ bnsums,
    const float* __restrict__ gamma, const float* __restrict__ beta,
    const float* __restrict__ gate_W, const float* __restrict__ gate_b,
    float* __restrict__ h, float* __restrict__ gatebuf, int N) {
    int idx = blockIdx.x * 256 + threadIdx.x;
    if (idx >= N * 64) return;
    int c = idx & 63, n = idx >> 6;
    float invN = 1.f / (float)N;
    float mean = bnsums[c] * invN;
    float var = bnsums[64 + c] * invN - mean * mean;
    float scale = gamma[c] * rsqrtf(var + 1e-5f);
    float shift = beta[c] - mean * scale;
    float o = outbuf[idx] * scale + shift;
    o = (o > 0.f) ? o : 0.01f * o;
    float hn = h[idx] + o;
    h[idx] = hn;
    float g = hn * gate_W[c];
#pragma unroll
    for (int off = 32; off; off >>= 1) g += __shfl_xor(g, off);
    if (c == 0) gatebuf[n] = g + gate_b[0];
}

// ---------------- pooling (max fused into acc) ----------------

__global__ __launch_bounds__(256) void pool_acc_kernel(
    const float* __restrict__ h, const float* __restrict__ gatebuf,
    const int* __restrict__ batch,
    float* __restrict__ pacc, float* __restrict__ pden, int N) {
    int b = blockIdx.x >> 3, chunk = blockIdx.x & 7;
    int lo = 0, hi = N;
    while (lo < hi) { int mid = (lo + hi) >> 1; if (batch[mid] < b) lo = mid + 1; else hi = mid; }
    int start = lo;
    lo = start; hi = N;
    while (lo < hi) { int mid = (lo + hi) >> 1; if (batch[mid] <= b) lo = mid + 1; else hi = mid; }
    int end = lo;
    int t = threadIdx.x, lane = t & 63, wid = t >> 6;
    __shared__ float sm[4];
    float mx = -1e30f;
    for (int n = start + t; n < end; n += 256) mx = fmaxf(mx, gatebuf[n]);
#pragma unroll
    for (int off = 32; off; off >>= 1) mx = fmaxf(mx, __shfl_xor(mx, off));
    if (lane == 0) sm[wid] = mx;
    __syncthreads();
    float mb = fmaxf(fmaxf(sm[0], sm[1]), fmaxf(sm[2], sm[3]));
    int gwid = chunk * 4 + wid;
    float acc = 0.f, den = 0.f;
    for (int n = start + gwid; n < end; n += 32) {
        float ge = __expf(gatebuf[n] - mb);
        acc += ge * h[(size_t)n * 64 + lane];
        den += ge;
    }
    __shared__ float sacc[4][64];
    __shared__ float sden[4];
    sacc[wid][lane] = acc;
    if (lane == 0) sden[wid] = den;
    __syncthreads();
    if (wid == 0) {
        pacc[(size_t)blockIdx.x * 64 + lane] =
            sacc[0][lane] + sacc[1][lane] + sacc[2][lane] + sacc[3][lane];
        if (lane == 0) pden[blockIdx.x] = sden[0] + sden[1] + sden[2] + sden[3];
    }
}

__global__ void pool_fin_kernel(const float* __restrict__ pacc, const float* __restrict__ pden,
                                const float* __restrict__ out_W, const float* __restrict__ out_b,
                                float* __restrict__ out) {
    int b = blockIdx.x, c = threadIdx.x;
    float pc = 0.f, dv = 0.f;
#pragma unroll
    for (int j = 0; j < 8; ++j) {
        pc += pacc[(size_t)(b * 8 + j) * 64 + c];
        dv += pden[b * 8 + j];
    }
    float s = pc * out_W[c];
#pragma unroll
    for (int off = 32; off; off >>= 1) s += __shfl_xor(s, off);
    if (c == 0) {
        if (dv <= 0.f) dv = 1.f;
        float v = s / dv + out_b[0];
        out[b] = 1.f / (1.f + __expf(-v));
    }
}

// ---------------- host ----------------

extern "C" void kernel_launch(void* const* d_in, const int* in_sizes, int n_in,
                              void* d_out, int out_size, void* d_ws, size_t ws_size,
                              hipStream_t stream) {
    const float* x         = (const float*)d_in[0];
    const float* edge_attr = (const float*)d_in[1];
    const int*   edge_src  = (const int*)d_in[2];
    const int*   edge_dst  = (const int*)d_in[3];
    const int*   batch     = (const int*)d_in[4];
    const float* node_W    = (const float*)d_in[5];
    const float* node_b    = (const float*)d_in[6];
    const float* edge_W    = (const float*)d_in[7];
    const float* edge_b    = (const float*)d_in[8];
    const float* Wq        = (const float*)d_in[9];
    const float* bq        = (const float*)d_in[10];
    const float* Wk        = (const float*)d_in[11];
    const float* bk        = (const float*)d_in[12];
    const float* Wv        = (const float*)d_in[13];
    const float* bv        = (const float*)d_in[14];
    const float* We        = (const float*)d_in[15];
    const float* be        = (const float*)d_in[16];
    const float* Wskip     = (const float*)d_in[17];
    const float* bskip     = (const float*)d_in[18];
    const float* gamma     = (const float*)d_in[19];
    const float* beta      = (const float*)d_in[20];
    const float* gate_W    = (const float*)d_in[21];
    const float* gate_b    = (const float*)d_in[22];
    const float* out_W     = (const float*)d_in[23];
    const float* out_b     = (const float*)d_in[24];
    float* out = (float*)d_out;

    const int N = in_sizes[0] / 16;
    const int E = in_sizes[2];
    const int nba = (N + 15) / 16;   // attn blocks: 16 nodes per block

    char* ws = (char*)d_ws;
    size_t off = 0;
    auto alloc = [&](size_t bytes) {
        size_t o = off;
        off += (bytes + 255) & ~(size_t)255;
        return o;
    };
    float*    h        = (float*)(ws + alloc((size_t)N * 64 * 4));
    ushort_t* h_bf     = (ushort_t*)(ws + alloc((size_t)N * 64 * 2));
    ushort_t* qkv      = (ushort_t*)(ws + alloc((size_t)N * 384 * 2));
    float*    outbuf   = (float*)(ws + alloc((size_t)N * 64 * 4));
    float*    qcbuf    = (float*)(ws + alloc((size_t)N * 20 * 4));
    int*      rowptr   = (int*)(ws + alloc((size_t)(N + 1) * 4));
    int*      cursor   = (int*)(ws + alloc((size_t)N * 4));
    int*      counts   = (int*)(ws + alloc((size_t)N * 4));
    int*      bsums    = (int*)(ws + alloc(1024));
    int*      csr_src  = (int*)(ws + alloc((size_t)E * 4));
    float*    ea_perm  = (float*)(ws + alloc((size_t)E * 8 * 4));
    float*    Wc       = (float*)(ws + alloc(2 * 1024 * 4));
    float*    bcb      = (float*)(ws + alloc(2 * 128 * 4));
    ushort_t* Wall_arr = (ushort_t*)(ws + alloc(2 * 32768 * 2));
    float*    Wall_b   = (float*)(ws + alloc(2 * 512 * 4));
    float*    bnsums   = (float*)(ws + alloc(128 * 4));
    float*    gatebuf  = (float*)(ws + alloc((size_t)N * 4));
    float*    pacc     = (float*)(ws + alloc((size_t)nba * 128 * 4));
    float*    pden     = (float*)(ws + alloc(512 * 4));
    int*      hist     = (int*)(ws + alloc(256));
    int*      perm     = (int*)(ws + alloc((size_t)N * 4));
    if (off > ws_size) return;

    int O0 = (N * 64 + 255) / 256;
    int O1 = O0 + (N + 255) / 256;
    int O2 = O1 + 9;
    int O3 = O2 + 228;
    setup_kernel<<<O3, 256, 0, stream>>>(
        x, node_W, node_b, edge_W, edge_b, We, be, Wq, bq, Wk, bk, Wv, bv, Wskip, bskip,
        h, h_bf, counts, Wc, bcb, Wall_arr, Wall_b, O0, O1, O2, N);
    combine2_kernel<<<10, 256, 0, stream>>>(Wq, bq, Wc, bcb, Wall_arr, Wall_b);

    csr_count_kernel<<<(E + 255) / 256, 256, 0, stream>>>(edge_dst, counts, hist, E);
    deg_hist_kernel<<<(N + 255) / 256, 256, 0, stream>>>(counts, hist, N);
    int nb = (N + 255) / 256;
    scan1_kernel<<<nb, 256, 0, stream>>>(counts, rowptr, bsums, N);
    scan3_kernel<<<nb, 256, 0, stream>>>(rowptr, bsums, cursor, N, E, nb);
    deg_scan_kernel<<<1, 64, 0, stream>>>(hist);
    csr_fill_kernel<<<(E + 255) / 256, 256, 0, stream>>>(edge_dst, edge_src, edge_attr,
                                                         cursor, csr_src, ea_perm, E);
    perm_scatter_kernel<<<(N + 255) / 256, 256, 0, stream>>>(counts, hist, perm, N);

    // layer 0
    qkv_mfma_kernel<<<(N + 31) / 32, 256, 0, stream>>>(
        h_bf, Wall_arr, Wall_b, qkv, outbuf, qcbuf, N);
    attn_kernel<<<nba, 256, 0, stream>>>(qkv, qcbuf, csr_src, ea_perm,
                                         rowptr, perm, Wc, bcb, outbuf, pacc, N);
    bnreduce_kernel<<<128, 256, 0, stream>>>(pacc, bnsums, nba);
    bnqkv_kernel<<<(N + 31) / 32, 256, 0, stream>>>(
        outbuf, bnsums, gamma, beta, h,
        Wall_arr + 32768, Wall_b + 512, qkv, outbuf, qcbuf, N);

    // layer 1
    attn_kernel<<<nba, 256, 0, stream>>>(qkv, qcbuf, csr_src, ea_perm,
                                         rowptr, perm, Wc + 1024, bcb + 128,
                                         outbuf, pacc, N);
    bnreduce_kernel<<<128, 256, 0, stream>>>(pacc, bnsums, nba);
    bnapply_kernel<<<(N * 64 + 255) / 256, 256, 0, stream>>>(
        outbuf, bnsums, gamma + 64, beta + 64, gate_W, gate_b, h, gatebuf, N);

    pool_acc_kernel<<<512, 256, 0, stream>>>(h, gatebuf, batch, pacc, pden, N);
    pool_fin_kernel<<<64, 64, 0, stream>>>(pacc, pden, out_W, out_b, out);
}

// Round 3
// 400.818 us; speedup vs baseline: 1.7970x; 1.7970x over previous
//
#include <hip/hip_runtime.h>
#include <hip/hip_bf16.h>

typedef unsigned short ushort_t;
typedef __attribute__((ext_vector_type(8))) short short8;
typedef __attribute__((ext_vector_type(4))) float float4v;

__device__ __forceinline__ float bfu_lo(unsigned u) {
    return __uint_as_float(u << 16);
}
__device__ __forceinline__ float bfu_hi(unsigned u) {
    return __uint_as_float(u & 0xffff0000u);
}
__device__ __forceinline__ ushort_t f2bf(float f) {
    __hip_bfloat16 h = __float2bfloat16(f);
    return *reinterpret_cast<ushort_t*>(&h);
}

// Wall layout per layer: 30 col-tiles (466 cols used), tile = 1024 ushorts:
//   idx = ct*1024 + kch*512 + lane*8 + j
// cols: 0..127 q | 128..255 k | 256..383 v | 384..447 skip | 448..465 qc

// ---------------- fused setup ----------------

__global__ __launch_bounds__(256) void setup_kernel(
    const float* __restrict__ x, const float* __restrict__ node_W,
    const float* __restrict__ node_b,
    const float* __restrict__ edge_W, const float* __restrict__ edge_b,
    const float* __restrict__ We, const float* __restrict__ be,
    const float* __restrict__ Wq, const float* __restrict__ bq,
    const float* __restrict__ Wk, const float* __restrict__ bk,
    const float* __restrict__ Wv, const float* __restrict__ bv,
    const float* __restrict__ Wskip, const float* __restrict__ bskip,
    float* __restrict__ h, ushort_t* __restrict__ h_bf,
    int* __restrict__ counts,
    float* __restrict__ Wc, float* __restrict__ bcb,
    ushort_t* __restrict__ Wall_arr, float* __restrict__ Wall_bias,
    int O0, int O1, int O2, int N) {
    int b = blockIdx.x, t = threadIdx.x;
    if (b < O0) {
        int idx = b * 256 + t;
        if (idx < N * 64) {
            int n = idx >> 6, c = idx & 63;
            float acc = node_b[c];
#pragma unroll
            for (int j = 0; j < 16; ++j) acc += x[n * 16 + j] * node_W[j * 64 + c];
            h[idx] = acc;
            h_bf[idx] = f2bf(acc);
        }
    } else if (b < O1) {
        int i = (b - O0) * 256 + t;
        if (i < N) counts[i] = 0;
    } else if (b < O2) {
        int tid = (b - O1) * 256 + t;
        if (tid < 2048) {
            int l = tid >> 10, d = (tid >> 7) & 7, j = tid & 127;
            float s = 0.f;
            for (int m = 0; m < 64; ++m) s += edge_W[d * 64 + m] * We[l * 8192 + m * 128 + j];
            Wc[l * 1024 + d * 128 + j] = s;
        } else if (tid < 2048 + 256) {
            int u = tid - 2048;
            int l = u >> 7, j = u & 127;
            float s = be[l * 128 + j];
            for (int m = 0; m < 64; ++m) s += edge_b[m] * We[l * 8192 + m * 128 + j];
            bcb[l * 128 + j] = s;
        }
    } else {
        int tid = (b - O2) * 256 + t;
        if (tid < 2 * 28672) {
            int l = tid / 28672, u = tid % 28672;
            int j = u & 7, ln = (u >> 3) & 63, kch = (u >> 9) & 1, ct = u >> 10;
            int nn = ln & 15, quad = ln >> 4;
            int k = kch * 32 + quad * 8 + j;
            int col = ct * 16 + nn;
            float v;
            if (col < 128)      v = Wq[l * 8192 + k * 128 + col];
            else if (col < 256) v = Wk[l * 8192 + k * 128 + col - 128];
            else if (col < 384) v = Wv[l * 8192 + k * 128 + col - 256];
            else                v = Wskip[l * 4096 + k * 64 + col - 384];
            Wall_arr[(size_t)l * 32768 + ct * 1024 + kch * 512 + ln * 8 + j] = f2bf(v);
        } else if (tid < 2 * 28672 + 2 * 448) {
            int u = tid - 2 * 28672;
            int l = u / 448, col = u % 448;
            float v;
            if (col < 128)      v = bq[l * 128 + col];
            else if (col < 256) v = bk[l * 128 + col - 128];
            else if (col < 384) v = bv[l * 128 + col - 256];
            else                v = bskip[l * 64 + col - 384];
            Wall_bias[l * 512 + col] = v;
        }
    }
}

// combine2: qc composed weights into Wall fragments
__global__ void combine2_kernel(const float* __restrict__ Wq, const float* __restrict__ bq,
                                const float* __restrict__ Wc, const float* __restrict__ bcb,
                                ushort_t* __restrict__ Wall_arr, float* __restrict__ Wall_bias) {
    int tid = blockIdx.x * 256 + threadIdx.x;
    if (tid < 2304) {
        int l = tid / 1152, u = tid % 1152, k = u / 18, j = u % 18;
        float s = 0.f;
        if (j < 16) {
            int hh = j >> 3, d = j & 7;
            for (int c = 0; c < 64; ++c)
                s += Wq[l * 8192 + k * 128 + hh * 64 + c] * Wc[l * 1024 + d * 128 + hh * 64 + c];
        } else {
            int hh = j - 16;
            for (int c = 0; c < 64; ++c)
                s += Wq[l * 8192 + k * 128 + hh * 64 + c] * bcb[l * 128 + hh * 64 + c];
        }
        s *= 0.125f;
        int col = 448 + j;
        int ct = col >> 4, nn = col & 15;
        int kch = k >> 5, quad = (k >> 3) & 3, jj = k & 7;
        int ln = quad * 16 + nn;
        Wall_arr[(size_t)l * 32768 + ct * 1024 + kch * 512 + ln * 8 + jj] = f2bf(s);
    } else if (tid < 2304 + 36) {
        int u = tid - 2304;
        int l = u / 18, j = u % 18;
        float s = 0.f;
        if (j < 16) {
            int hh = j >> 3, d = j & 7;
            for (int c = 0; c < 64; ++c)
                s += bq[l * 128 + hh * 64 + c] * Wc[l * 1024 + d * 128 + hh * 64 + c];
        } else {
            int hh = j - 16;
            for (int c = 0; c < 64; ++c)
                s += bq[l * 128 + hh * 64 + c] * bcb[l * 128 + hh * 64 + c];
        }
        Wall_bias[l * 512 + 448 + j] = 0.125f * s;
    }
}

// ---------------- CSR build + degree-sort ----------------

__global__ void csr_count_kernel(const int* __restrict__ dst, int* __restrict__ counts,
                                 int* __restrict__ hist, int E) {
    if (blockIdx.x == 0 && threadIdx.x < 64) hist[threadIdx.x] = 0;
    int e = blockIdx.x * 256 + threadIdx.x;
    if (e < E) atomicAdd(&counts[dst[e]], 1);
}

// two-level histogram: LDS aggregate per block, then <=64 global atomics/block
__global__ __launch_bounds__(256) void deg_hist_kernel(const int* __restrict__ counts,
                                                       int* __restrict__ hist, int N) {
    __shared__ int lh[64];
    int t = threadIdx.x;
    if (t < 64) lh[t] = 0;
    __syncthreads();
    int n = blockIdx.x * 256 + t;
    if (n < N) {
        int b = 63 - min(counts[n], 63);   // descending degree order
        atomicAdd(&lh[b], 1);
    }
    __syncthreads();
    if (t < 64 && lh[t] > 0) atomicAdd(&hist[t], lh[t]);
}

__global__ void deg_scan_kernel(int* __restrict__ hist) {
    int t = threadIdx.x;   // 64 threads, 1 wave
    int v = hist[t];
    int s = v;
#pragma unroll
    for (int d = 1; d < 64; d <<= 1) {
        int x = __shfl_up(s, d);
        if (t >= d) s += x;
    }
    hist[t] = s - v;       // exclusive prefix
}

// two-level scatter: block reserves a range per bucket with ONE global atomic,
// threads place themselves via their LDS-local rank.
__global__ __launch_bounds__(256) void perm_scatter_kernel(const int* __restrict__ counts,
                                                           int* __restrict__ hist,
                                                           int* __restrict__ perm, int N) {
    __shared__ int lh[64];
    __shared__ int base[64];
    int t = threadIdx.x;
    if (t < 64) lh[t] = 0;
    __syncthreads();
    int n = blockIdx.x * 256 + t;
    bool act = (n < N);
    int b = 0, lrank = 0;
    if (act) {
        b = 63 - min(counts[n], 63);
        lrank = atomicAdd(&lh[b], 1);
    }
    __syncthreads();
    if (t < 64) base[t] = (lh[t] > 0) ? atomicAdd(&hist[t], lh[t]) : 0;
    __syncthreads();
    if (act) perm[base[b] + lrank] = n;
}

__global__ void scan1_kernel(const int* __restrict__ counts, int* __restrict__ rowptr,
                             int* __restrict__ bsums, int N) {
    __shared__ int s[256];
    int t = threadIdx.x, i = blockIdx.x * 256 + t;
    int v = (i < N) ? counts[i] : 0;
    s[t] = v;
    __syncthreads();
    for (int d = 1; d < 256; d <<= 1) {
        int x = (t >= d) ? s[t - d] : 0;
        __syncthreads();
        s[t] += x;
        __syncthreads();
    }
    if (i < N) rowptr[i] = s[t] - v;
    if (t == 255) bsums[blockIdx.x] = s[255];
}

// scan3 with scan2 folded in
__global__ void scan3_kernel(int* __restrict__ rowptr, const int* __restrict__ bsums,
                             int* __restrict__ cursor, int N, int E, int nb) {
    __shared__ int sh[256];
    int t = threadIdx.x;
    int v = (t < nb) ? bsums[t] : 0;
    sh[t] = v;
    __syncthreads();
    for (int d = 1; d < 256; d <<= 1) {
        int x = (t >= d) ? sh[t - d] : 0;
        __syncthreads();
        sh[t] += x;
        __syncthreads();
    }
    int blk = blockIdx.x;
    int offv = (blk == 0) ? 0 : sh[blk - 1];
    int i = blk * 256 + t;
    if (i < N) {
        int r = rowptr[i] + offv;
        rowptr[i] = r;
        cursor[i] = r;
    }
    if (i == 0) rowptr[N] = E;
}

__global__ void csr_fill_kernel(const int* __restrict__ dst, const int* __restrict__ src,
                                const float* __restrict__ edge_attr, int* __restrict__ cursor,
                                int* __restrict__ csr_src, float* __restrict__ ea_perm, int E) {
    int e = blockIdx.x * 256 + threadIdx.x;
    if (e < E) {
        int pos = atomicAdd(&cursor[dst[e]], 1);
        csr_src[pos] = src[e] * 768 + 256;
        float4 a0 = *(const float4*)(edge_attr + (size_t)e * 8);
        float4 a1 = *(const float4*)(edge_attr + (size_t)e * 8 + 4);
        *(float4*)(ea_perm + (size_t)pos * 8) = a0;
        *(float4*)(ea_perm + (size_t)pos * 8 + 4) = a1;
    }
}

// ---------------- per-layer MFMA GEMM: [32 x 64] @ [64 x 466] (from global h_bf) ----

__global__ __launch_bounds__(256) void qkv_mfma_kernel(
    const ushort_t* __restrict__ h_bf,
    const ushort_t* __restrict__ Wall_arr, const float* __restrict__ Wall_bias,
    ushort_t* __restrict__ qkv, float* __restrict__ outbuf, float* __restrict__ qcbuf, int N) {
    int wave = threadIdx.x >> 6, lane = threadIdx.x & 63;
    int quad = lane >> 4, nn = lane & 15;
    int n0 = blockIdx.x * 32;
    int nodeA = n0 + nn;       if (nodeA >= N) nodeA = N - 1;
    int nodeB = n0 + 16 + nn;  if (nodeB >= N) nodeB = N - 1;
    const ushort_t* apA = h_bf + (size_t)nodeA * 64 + quad * 8;
    const ushort_t* apB = h_bf + (size_t)nodeB * 64 + quad * 8;
    short8 aA0 = *(const short8*)apA;
    short8 aA1 = *(const short8*)(apA + 32);
    short8 aB0 = *(const short8*)apB;
    short8 aB1 = *(const short8*)(apB + 32);
    int ct_start = (wave < 2) ? wave * 8 : (16 + (wave - 2) * 7);
    int ct_cnt = (wave < 2) ? 8 : 7;
    for (int i = 0; i < ct_cnt; ++i) {
        int ct = ct_start + i;
        const ushort_t* bp = Wall_arr + (size_t)ct * 1024 + lane * 8;
        short8 b0 = *(const short8*)bp;
        short8 b1 = *(const short8*)(bp + 512);
        float4v cA = {0.f, 0.f, 0.f, 0.f};
        float4v cB = {0.f, 0.f, 0.f, 0.f};
        cA = __builtin_amdgcn_mfma_f32_16x16x32_bf16(aA0, b0, cA, 0, 0, 0);
        cA = __builtin_amdgcn_mfma_f32_16x16x32_bf16(aA1, b1, cA, 0, 0, 0);
        cB = __builtin_amdgcn_mfma_f32_16x16x32_bf16(aB0, b0, cB, 0, 0, 0);
        cB = __builtin_amdgcn_mfma_f32_16x16x32_bf16(aB1, b1, cB, 0, 0, 0);
        int col = ct * 16 + nn;
        float bias = Wall_bias[col];
#pragma unroll
        for (int g = 0; g < 2; ++g) {
            float4v c = (g == 0) ? cA : cB;
            int nbase = n0 + g * 16 + quad * 4;
            if (col < 384) {
                int cm;
                if (col < 128) cm = col;
                else if (col < 256) { int cc = col - 128; cm = 128 + ((cc >> 1) << 2) + (cc & 1); }
                else { int cc = col - 256; cm = 128 + ((cc >> 1) << 2) + 2 + (cc & 1); }
                ushort_t* qp = qkv + (size_t)nbase * 384 + cm;
#pragma unroll
                for (int r = 0; r < 4; ++r)
                    if (nbase + r < N) qp[(size_t)r * 384] = f2bf(c[r] + bias);
            } else if (col < 448) {
                float* op = outbuf + (size_t)nbase * 64 + (col - 448 + 64);
#pragma unroll
                for (int r = 0; r < 4; ++r)
                    if (nbase + r < N) op[(size_t)r * 64] = c[r] + bias;
            } else if (col < 466) {
                float* qp2 = qcbuf + (size_t)nbase * 20 + (col - 448);
#pragma unroll
                for (int r = 0; r < 4; ++r)
                    if (nbase + r < N) qp2[(size_t)r * 20] = c[r] + bias;
            }
        }
    }
}

// ---------------- fused BN-apply(l) + qkv-MFMA(l+1): 32 nodes/block ----------------

__global__ __launch_bounds__(256) void bnqkv_kernel(
    const float* __restrict__ outbuf_in, const float* __restrict__ bnsums,
    const float* __restrict__ gamma, const float* __restrict__ beta,
    float* __restrict__ h,
    const ushort_t* __restrict__ Wall_arr, const float* __restrict__ Wall_bias,
    ushort_t* __restrict__ qkv, float* __restrict__ outbuf, float* __restrict__ qcbuf, int N) {
    __shared__ ushort_t hb[32 * 64];
    __shared__ float ss_scale[64], ss_shift[64];
    int t = threadIdx.x;
    if (t < 64) {
        float invN = 1.f / (float)N;
        float mean = bnsums[t] * invN;
        float var = bnsums[64 + t] * invN - mean * mean;
        float sc = gamma[t] * rsqrtf(var + 1e-5f);
        ss_scale[t] = sc;
        ss_shift[t] = beta[t] - mean * sc;
    }
    __syncthreads();
    int n0 = blockIdx.x * 32;
    int c = t & 63;
    float sc = ss_scale[c], sh = ss_shift[c];
#pragma unroll
    for (int i = 0; i < 8; ++i) {
        int li = t + i * 256;
        int gidx = n0 * 64 + li;
        float hn = 0.f;
        if (gidx < N * 64) {
            float o = outbuf_in[gidx] * sc + sh;
            o = (o > 0.f) ? o : 0.01f * o;
            hn = h[gidx] + o;
            h[gidx] = hn;
        }
        hb[li] = f2bf(hn);
    }
    __syncthreads();
    int wave = t >> 6, lane = t & 63;
    int quad = lane >> 4, nn = lane & 15;
    const ushort_t* apA = hb + nn * 64 + quad * 8;
    const ushort_t* apB = hb + (16 + nn) * 64 + quad * 8;
    short8 aA0 = *(const short8*)apA;
    short8 aA1 = *(const short8*)(apA + 32);
    short8 aB0 = *(const short8*)apB;
    short8 aB1 = *(const short8*)(apB + 32);
    int ct_start = (wave < 2) ? wave * 8 : (16 + (wave - 2) * 7);
    int ct_cnt = (wave < 2) ? 8 : 7;
    for (int i = 0; i < ct_cnt; ++i) {
        int ct = ct_start + i;
        const ushort_t* bp = Wall_arr + (size_t)ct * 1024 + lane * 8;
        short8 b0 = *(const short8*)bp;
        short8 b1 = *(const short8*)(bp + 512);
        float4v cA = {0.f, 0.f, 0.f, 0.f};
        float4v cB = {0.f, 0.f, 0.f, 0.f};
        cA = __builtin_amdgcn_mfma_f32_16x16x32_bf16(aA0, b0, cA, 0, 0, 0);
        cA = __builtin_amdgcn_mfma_f32_16x16x32_bf16(aA1, b1, cA, 0, 0, 0);
        cB = __builtin_amdgcn_mfma_f32_16x16x32_bf16(aB0, b0, cB, 0, 0, 0);
        cB = __builtin_amdgcn_mfma_f32_16x16x32_bf16(aB1, b1, cB, 0, 0, 0);
        int col = ct * 16 + nn;
        float bias = Wall_bias[col];
#pragma unroll
        for (int g = 0; g < 2; ++g) {
            float4v cc2 = (g == 0) ? cA : cB;
            int nbase = n0 + g * 16 + quad * 4;
            if (col < 384) {
                int cm;
                if (col < 128) cm = col;
                else if (col < 256) { int cv = col - 128; cm = 128 + ((cv >> 1) << 2) + (cv & 1); }
                else { int cv = col - 256; cm = 128 + ((cv >> 1) << 2) + 2 + (cv & 1); }
                ushort_t* qp = qkv + (size_t)nbase * 384 + cm;
#pragma unroll
                for (int r = 0; r < 4; ++r)
                    if (nbase + r < N) qp[(size_t)r * 384] = f2bf(cc2[r] + bias);
            } else if (col < 448) {
                float* op = outbuf + (size_t)nbase * 64 + (col - 448 + 64);
#pragma unroll
                for (int r = 0; r < 4; ++r)
                    if (nbase + r < N) op[(size_t)r * 64] = cc2[r] + bias;
            } else if (col < 466) {
                float* qp2 = qcbuf + (size_t)nbase * 20 + (col - 448);
#pragma unroll
                for (int r = 0; r < 4; ++r)
                    if (nbase + r < N) qp2[(size_t)r * 20] = cc2[r] + bias;
            }
        }
    }
}

// ---------------- attention: 16-lane node groups, degree-sorted, 2 edges/iter ------
// lane l16 in [0,16): holds channels 8*l16 .. 8*l16+7 (l16<8 -> head 0, else head 1).
// Nodes assigned via perm[] (descending degree) so the 4 groups of a wave have
// near-equal degree (wdeg ~= deg) and long blocks launch first (LPT).

__global__ __launch_bounds__(256) void attn_kernel(
    const ushort_t* __restrict__ qkv, const float* __restrict__ qcbuf,
    const int* __restrict__ csr_src, const float* __restrict__ ea_perm,
    const int* __restrict__ rowptr, const int* __restrict__ perm,
    const float* __restrict__ Wc, const float* __restrict__ bcb,
    float* __restrict__ outbuf, float* __restrict__ part, int N) {
    __shared__ float Wc_s[1024];
    __shared__ float bc_s[128];
    __shared__ float stat[4][4][2][64];   // [wid][grp][sa|sq][chan]
    int t = threadIdx.x;
    for (int i = t; i < 1024; i += 256) Wc_s[i] = Wc[i];
    if (t < 128) bc_s[t] = bcb[t];
    {
        float* sf = &stat[0][0][0][0];
        for (int i = t; i < 2048; i += 256) sf[i] = 0.f;
    }
    __syncthreads();
    int lane = t & 63, wid = t >> 6;
    int grp = lane >> 4, l16 = lane & 15;
    int head = l16 >> 3, l8 = l16 & 7;
    const char* qkvb = (const char*)qkv;

    int slot = blockIdx.x * 16 + wid * 4 + grp;
    bool active = (slot < N);
    int nn = perm[active ? slot : (N - 1)];
    int start = rowptr[nn];
    int deg = active ? (rowptr[nn + 1] - start) : 0;
    int wdeg = deg;
    wdeg = max(wdeg, __shfl_xor(wdeg, 16));
    wdeg = max(wdeg, __shfl_xor(wdeg, 32));

    float lsum = 0.f;
    float vacc[8] = {0.f, 0.f, 0.f, 0.f, 0.f, 0.f, 0.f, 0.f};
    float se[8]   = {0.f, 0.f, 0.f, 0.f, 0.f, 0.f, 0.f, 0.f};

    if (wdeg > 0) {
        // q fragment: 8 channels per lane, packed bf16 pairs
        uint4 qr = *(const uint4*)(qkvb + (size_t)nn * 768 + 16 * l16);
        float qf0 = bfu_lo(qr.x), qf1 = bfu_hi(qr.x);
        float qf2 = bfu_lo(qr.y), qf3 = bfu_hi(qr.y);
        float qf4 = bfu_lo(qr.z), qf5 = bfu_hi(qr.z);
        float qf6 = bfu_lo(qr.w), qf7 = bfu_hi(qr.w);
        const float* qcp = qcbuf + (size_t)nn * 20;
        float4 qcA = *(const float4*)(qcp + head * 8);
        float4 qcB = *(const float4*)(qcp + head * 8 + 4);
        float qb = qcp[16 + head];

        bool dpos = (deg > 0);
        int dclamp = dpos ? (deg - 1) : 0;

        // 16-edge offset window held across the group's lanes
        int offL = csr_src[dpos ? (start + min(l16, dclamp)) : 0];

        int i1 = min(1, wdeg - 1);
        int o0 = __shfl(offL, grp * 16);
        int o1 = __shfl(offL, grp * 16 + i1);
        uint4 ca0 = *(const uint4*)(qkvb + (size_t)(unsigned)o0 + 32 * l16);
        uint4 cb0 = *(const uint4*)(qkvb + (size_t)(unsigned)o0 + 32 * l16 + 16);
        uint4 ca1 = *(const uint4*)(qkvb + (size_t)(unsigned)o1 + 32 * l16);
        uint4 cb1 = *(const uint4*)(qkvb + (size_t)(unsigned)o1 + 32 * l16 + 16);
        int g0 = dpos ? start : 0;
        int g1 = dpos ? (start + min(i1, dclamp)) : 0;
        float4 e00 = *(const float4*)(ea_perm + (size_t)g0 * 8);
        float4 e01 = *(const float4*)(ea_perm + (size_t)g0 * 8 + 4);
        float4 e10 = *(const float4*)(ea_perm + (size_t)g1 * 8);
        float4 e11 = *(const float4*)(ea_perm + (size_t)g1 * 8 + 4);

        for (int it = 0; it < wdeg; it += 2) {
            int p0 = it + 2;
            if ((p0 & 15) == 0 && p0 < wdeg)
                offL = csr_src[dpos ? (start + min(p0 + l16, dclamp)) : 0];
            int q0 = min(p0, wdeg - 1);
            int q1 = min(p0 + 1, wdeg - 1);
            int on0 = __shfl(offL, grp * 16 + (q0 & 15));
            int on1 = __shfl(offL, grp * 16 + (q1 & 15));
            uint4 na0 = *(const uint4*)(qkvb + (size_t)(unsigned)on0 + 32 * l16);
            uint4 nb0 = *(const uint4*)(qkvb + (size_t)(unsigned)on0 + 32 * l16 + 16);
            uint4 na1 = *(const uint4*)(qkvb + (size_t)(unsigned)on1 + 32 * l16);
            uint4 nb1 = *(const uint4*)(qkvb + (size_t)(unsigned)on1 + 32 * l16 + 16);
            int gn0 = dpos ? (start + min(q0, dclamp)) : 0;
            int gn1 = dpos ? (start + min(q1, dclamp)) : 0;
            float4 f00 = *(const float4*)(ea_perm + (size_t)gn0 * 8);
            float4 f01 = *(const float4*)(ea_perm + (size_t)gn0 * 8 + 4);
            float4 f10 = *(const float4*)(ea_perm + (size_t)gn1 * 8);
            float4 f11 = *(const float4*)(ea_perm + (size_t)gn1 * 8 + 4);

            float dt0 = qf0 * bfu_lo(ca0.x) + qf1 * bfu_hi(ca0.x)
                      + qf2 * bfu_lo(ca0.z) + qf3 * bfu_hi(ca0.z)
                      + qf4 * bfu_lo(cb0.x) + qf5 * bfu_hi(cb0.x)
                      + qf6 * bfu_lo(cb0.z) + qf7 * bfu_hi(cb0.z);
            float dt1 = qf0 * bfu_lo(ca1.x) + qf1 * bfu_hi(ca1.x)
                      + qf2 * bfu_lo(ca1.z) + qf3 * bfu_hi(ca1.z)
                      + qf4 * bfu_lo(cb1.x) + qf5 * bfu_hi(cb1.x)
                      + qf6 * bfu_lo(cb1.z) + qf7 * bfu_hi(cb1.z);
            dt0 += __shfl_xor(dt0, 1); dt1 += __shfl_xor(dt1, 1);
            dt0 += __shfl_xor(dt0, 2); dt1 += __shfl_xor(dt1, 2);
            dt0 += __shfl_xor(dt0, 4); dt1 += __shfl_xor(dt1, 4);
            float s00 = dt0 * 0.125f
                      + qcA.x * e00.x + qcA.y * e00.y + qcA.z * e00.z + qcA.w * e00.w
                      + qcB.x * e01.x + qcB.y * e01.y + qcB.z * e01.z + qcB.w * e01.w
                      + qb;
            float s01 = dt1 * 0.125f
                      + qcA.x * e10.x + qcA.y * e10.y + qcA.z * e10.z + qcA.w * e10.w
                      + qcB.x * e11.x + qcB.y * e11.y + qcB.z * e11.z + qcB.w * e11.w
                      + qb;
            float p0v = (it < deg) ? __expf(fmaxf(s00, -60.f)) : 0.f;
            float p1v = (it + 1 < deg) ? __expf(fmaxf(s01, -60.f)) : 0.f;
            lsum += p0v + p1v;
            vacc[0] += p0v * bfu_lo(ca0.y) + p1v * bfu_lo(ca1.y);
            vacc[1] += p0v * bfu_hi(ca0.y) + p1v * bfu_hi(ca1.y);
            vacc[2] += p0v * bfu_lo(ca0.w) + p1v * bfu_lo(ca1.w);
            vacc[3] += p0v * bfu_hi(ca0.w) + p1v * bfu_hi(ca1.w);
            vacc[4] += p0v * bfu_lo(cb0.y) + p1v * bfu_lo(cb1.y);
            vacc[5] += p0v * bfu_hi(cb0.y) + p1v * bfu_hi(cb1.y);
            vacc[6] += p0v * bfu_lo(cb0.w) + p1v * bfu_lo(cb1.w);
            vacc[7] += p0v * bfu_hi(cb0.w) + p1v * bfu_hi(cb1.w);
            se[0] += p0v * e00.x + p1v * e10.x;
            se[1] += p0v * e00.y + p1v * e10.y;
            se[2] += p0v * e00.z + p1v * e10.z;
            se[3] += p0v * e00.w + p1v * e10.w;
            se[4] += p0v * e01.x + p1v * e11.x;
            se[5] += p0v * e01.y + p1v * e11.y;
            se[6] += p0v * e01.z + p1v * e11.z;
            se[7] += p0v * e01.w + p1v * e11.w;
            ca0 = na0; cb0 = nb0; ca1 = na1; cb1 = nb1;
            e00 = f00; e01 = f01; e10 = f10; e11 = f11;
        }
    }

    if (active) {
        float inv = (deg > 0) ? (1.f / lsum) : 0.f;
        int jb = head * 64 + 8 * l8;
        float outv[8];
#pragma unroll
        for (int k2 = 0; k2 < 8; ++k2) {
            int j = jb + k2;
            float wv = lsum * bc_s[j];
#pragma unroll
            for (int m = 0; m < 8; ++m) wv += se[m] * Wc_s[m * 128 + j];
            float ox = (vacc[k2] + wv) * inv;
            float po = __shfl_xor(ox, 8);   // head exchange within group
            outv[k2] = 0.5f * (ox + po);
        }
        if (head == 0) {
            float* op = outbuf + (size_t)nn * 64 + 8 * l8;
            float4 c0 = *(const float4*)op;
            float4 c1 = *(const float4*)(op + 4);
            float fr[8];
            fr[0] = c0.x + outv[0]; fr[1] = c0.y + outv[1];
            fr[2] = c0.z + outv[2]; fr[3] = c0.w + outv[3];
            fr[4] = c1.x + outv[4]; fr[5] = c1.y + outv[5];
            fr[6] = c1.z + outv[6]; fr[7] = c1.w + outv[7];
            if (deg > 0) {
                *(float4*)op = make_float4(fr[0], fr[1], fr[2], fr[3]);
                *(float4*)(op + 4) = make_float4(fr[4], fr[5], fr[6], fr[7]);
            }
            float* sa = &stat[wid][grp][0][8 * l8];
            float* sq = &stat[wid][grp][1][8 * l8];
#pragma unroll
            for (int k2 = 0; k2 < 8; ++k2) {
                sa[k2] += fr[k2];
                sq[k2] += fr[k2] * fr[k2];
            }
        }
    }
    __syncthreads();
    if (t < 128) {
        int c = t & 63, qq = t >> 6;
        float s = 0.f;
#pragma unroll
        for (int w2 = 0; w2 < 4; ++w2)
#pragma unroll
            for (int g2 = 0; g2 < 4; ++g2) s += stat[w2][g2][qq][c];
        part[(size_t)blockIdx.x * 128 + t] = s;
    }
}

// ---------------- BN reduce + final-layer apply w/ gate ----------------

__global__ __launch_bounds__(256) void bnreduce_kernel(const float* __restrict__ part,
                                                       float* __restrict__ bnsums, int nb) {
    int s = blockIdx.x;  // 0..127
    int t = threadIdx.x;
    float a = 0.f;
    for (int b = t; b < nb; b += 256) a += part[(size_t)b * 128 + s];
    __shared__ float sh[256];
    sh[t] = a;
    __syncthreads();
    for (int d = 128; d; d >>= 1) {
        if (t < d) sh[t] += sh[t + d];
        __syncthreads();
    }
    if (t == 0) bnsums[s] = sh[0];
}

__global__ __launch_bounds__(256) void bnapply_kernel(
    const float* __restrict__ outbuf, const float* __restrict__ bnsums,
    const float* __restrict__ gamma, const float* __restrict__ beta,
    const float* __restrict__ gate_W, const float* __restrict__ gate_b,
    float* __restrict__ h, float* __restrict__ gatebuf, int N) {
    int idx = blockIdx.x * 256 + threadIdx.x;
    if (idx >= N * 64) return;
    int c = idx & 63, n = idx >> 6;
    float invN = 1.f / (float)N;
    float mean = bnsums[c] * invN;
    float var = bnsums[64 + c] * invN - mean * mean;
    float scale = gamma[c] * rsqrtf(var + 1e-5f);
    float shift = beta[c] - mean * scale;
    float o = outbuf[idx] * scale + shift;
    o = (o > 0.f) ? o : 0.01f * o;
    float hn = h[idx] + o;
    h[idx] = hn;
    float g = hn * gate_W[c];
#pragma unroll
    for (int off = 32; off; off >>= 1) g += __shfl_xor(g, off);
    if (c == 0) gatebuf[n] = g + gate_b[0];
}

// ---------------- pooling (max fused into acc) ----------------

__global__ __launch_bounds__(256) void pool_acc_kernel(
    const float* __restrict__ h, const float* __restrict__ gatebuf,
    const int* __restrict__ batch,
    float* __restrict__ pacc, float* __restrict__ pden, int N) {
    int b = blockIdx.x >> 3, chunk = blockIdx.x & 7;
    int lo = 0, hi = N;
    while (lo < hi) { int mid = (lo + hi) >> 1; if (batch[mid] < b) lo = mid + 1; else hi = mid; }
    int start = lo;
    lo = start; hi = N;
    while (lo < hi) { int mid = (lo + hi) >> 1; if (batch[mid] <= b) lo = mid + 1; else hi = mid; }
    int end = lo;
    int t = threadIdx.x, lane = t & 63, wid = t >> 6;
    __shared__ float sm[4];
    float mx = -1e30f;
    for (int n = start + t; n < end; n += 256) mx = fmaxf(mx, gatebuf[n]);
#pragma unroll
    for (int off = 32; off; off >>= 1) mx = fmaxf(mx, __shfl_xor(mx, off));
    if (lane == 0) sm[wid] = mx;
    __syncthreads();
    float mb = fmaxf(fmaxf(sm[0], sm[1]), fmaxf(sm[2], sm[3]));
    int gwid = chunk * 4 + wid;
    float acc = 0.f, den = 0.f;
    for (int n = start + gwid; n < end; n += 32) {
        float ge = __expf(gatebuf[n] - mb);
        acc += ge * h[(size_t)n * 64 + lane];
        den += ge;
    }
    __shared__ float sacc[4][64];
    __shared__ float sden[4];
    sacc[wid][lane] = acc;
    if (lane == 0) sden[wid] = den;
    __syncthreads();
    if (wid == 0) {
        pacc[(size_t)blockIdx.x * 64 + lane] =
            sacc[0][lane] + sacc[1][lane] + sacc[2][lane] + sacc[3][lane];
        if (lane == 0) pden[blockIdx.x] = sden[0] + sden[1] + sden[2] + sden[3];
    }
}

__global__ void pool_fin_kernel(const float* __restrict__ pacc, const float* __restrict__ pden,
                                const float* __restrict__ out_W, const float* __restrict__ out_b,
                                float* __restrict__ out) {
    int b = blockIdx.x, c = threadIdx.x;
    float pc = 0.f, dv = 0.f;
#pragma unroll
    for (int j = 0; j < 8; ++j) {
        pc += pacc[(size_t)(b * 8 + j) * 64 + c];
        dv += pden[b * 8 + j];
    }
    float s = pc * out_W[c];
#pragma unroll
    for (int off = 32; off; off >>= 1) s += __shfl_xor(s, off);
    if (c == 0) {
        if (dv <= 0.f) dv = 1.f;
        float v = s / dv + out_b[0];
        out[b] = 1.f / (1.f + __expf(-v));
    }
}

// ---------------- host ----------------

extern "C" void kernel_launch(void* const* d_in, const int* in_sizes, int n_in,
                              void* d_out, int out_size, void* d_ws, size_t ws_size,
                              hipStream_t stream) {
    const float* x         = (const float*)d_in[0];
    const float* edge_attr = (const float*)d_in[1];
    const int*   edge_src  = (const int*)d_in[2];
    const int*   edge_dst  = (const int*)d_in[3];
    const int*   batch     = (const int*)d_in[4];
    const float* node_W    = (const float*)d_in[5];
    const float* node_b    = (const float*)d_in[6];
    const float* edge_W    = (const float*)d_in[7];
    const float* edge_b    = (const float*)d_in[8];
    const float* Wq        = (const float*)d_in[9];
    const float* bq        = (const float*)d_in[10];
    const float* Wk        = (const float*)d_in[11];
    const float* bk        = (const float*)d_in[12];
    const float* Wv        = (const float*)d_in[13];
    const float* bv        = (const float*)d_in[14];
    const float* We        = (const float*)d_in[15];
    const float* be        = (const float*)d_in[16];
    const float* Wskip     = (const float*)d_in[17];
    const float* bskip     = (const float*)d_in[18];
    const float* gamma     = (const float*)d_in[19];
    const float* beta      = (const float*)d_in[20];
    const float* gate_W    = (const float*)d_in[21];
    const float* gate_b    = (const float*)d_in[22];
    const float* out_W     = (const float*)d_in[23];
    const float* out_b     = (const float*)d_in[24];
    float* out = (float*)d_out;

    const int N = in_sizes[0] / 16;
    const int E = in_sizes[2];
    const int nba = (N + 15) / 16;   // attn blocks: 16 nodes per block

    char* ws = (char*)d_ws;
    size_t off = 0;
    auto alloc = [&](size_t bytes) {
        size_t o = off;
        off += (bytes + 255) & ~(size_t)255;
        return o;
    };
    float*    h        = (float*)(ws + alloc((size_t)N * 64 * 4));
    ushort_t* h_bf     = (ushort_t*)(ws + alloc((size_t)N * 64 * 2));
    ushort_t* qkv      = (ushort_t*)(ws + alloc((size_t)N * 384 * 2));
    float*    outbuf   = (float*)(ws + alloc((size_t)N * 64 * 4));
    float*    qcbuf    = (float*)(ws + alloc((size_t)N * 20 * 4));
    int*      rowptr   = (int*)(ws + alloc((size_t)(N + 1) * 4));
    int*      cursor   = (int*)(ws + alloc((size_t)N * 4));
    int*      counts   = (int*)(ws + alloc((size_t)N * 4));
    int*      bsums    = (int*)(ws + alloc(1024));
    int*      csr_src  = (int*)(ws + alloc((size_t)E * 4));
    float*    ea_perm  = (float*)(ws + alloc((size_t)E * 8 * 4));
    float*    Wc       = (float*)(ws + alloc(2 * 1024 * 4));
    float*    bcb      = (float*)(ws + alloc(2 * 128 * 4));
    ushort_t* Wall_arr = (ushort_t*)(ws + alloc(2 * 32768 * 2));
    float*    Wall_b   = (float*)(ws + alloc(2 * 512 * 4));
    float*    bnsums   = (float*)(ws + alloc(128 * 4));
    float*    gatebuf  = (float*)(ws + alloc((size_t)N * 4));
    float*    pacc     = (float*)(ws + alloc((size_t)nba * 128 * 4));
    float*    pden     = (float*)(ws + alloc(512 * 4));
    int*      hist     = (int*)(ws + alloc(256));
    int*      perm     = (int*)(ws + alloc((size_t)N * 4));
    if (off > ws_size) return;

    int O0 = (N * 64 + 255) / 256;
    int O1 = O0 + (N + 255) / 256;
    int O2 = O1 + 9;
    int O3 = O2 + 228;
    setup_kernel<<<O3, 256, 0, stream>>>(
        x, node_W, node_b, edge_W, edge_b, We, be, Wq, bq, Wk, bk, Wv, bv, Wskip, bskip,
        h, h_bf, counts, Wc, bcb, Wall_arr, Wall_b, O0, O1, O2, N);
    combine2_kernel<<<10, 256, 0, stream>>>(Wq, bq, Wc, bcb, Wall_arr, Wall_b);

    csr_count_kernel<<<(E + 255) / 256, 256, 0, stream>>>(edge_dst, counts, hist, E);
    deg_hist_kernel<<<(N + 255) / 256, 256, 0, stream>>>(counts, hist, N);
    int nb = (N + 255) / 256;
    scan1_kernel<<<nb, 256, 0, stream>>>(counts, rowptr, bsums, N);
    scan3_kernel<<<nb, 256, 0, stream>>>(rowptr, bsums, cursor, N, E, nb);
    deg_scan_kernel<<<1, 64, 0, stream>>>(hist);
    csr_fill_kernel<<<(E + 255) / 256, 256, 0, stream>>>(edge_dst, edge_src, edge_attr,
                                                         cursor, csr_src, ea_perm, E);
    perm_scatter_kernel<<<(N + 255) / 256, 256, 0, stream>>>(counts, hist, perm, N);

    // layer 0
    qkv_mfma_kernel<<<(N + 31) / 32, 256, 0, stream>>>(
        h_bf, Wall_arr, Wall_b, qkv, outbuf, qcbuf, N);
    attn_kernel<<<nba, 256, 0, stream>>>(qkv, qcbuf, csr_src, ea_perm,
                                         rowptr, perm, Wc, bcb, outbuf, pacc, N);
    bnreduce_kernel<<<128, 256, 0, stream>>>(pacc, bnsums, nba);
    bnqkv_kernel<<<(N + 31) / 32, 256, 0, stream>>>(
        outbuf, bnsums, gamma, beta, h,
        Wall_arr + 32768, Wall_b + 512, qkv, outbuf, qcbuf, N);

    // layer 1
    attn_kernel<<<nba, 256, 0, stream>>>(qkv, qcbuf, csr_src, ea_perm,
                                         rowptr, perm, Wc + 1024, bcb + 128,
                                         outbuf, pacc, N);
    bnreduce_kernel<<<128, 256, 0, stream>>>(pacc, bnsums, nba);
    bnapply_kernel<<<(N * 64 + 255) / 256, 256, 0, stream>>>(
        outbuf, bnsums, gamma + 64, beta + 64, gate_W, gate_b, h, gatebuf, N);

    pool_acc_kernel<<<512, 256, 0, stream>>>(h, gatebuf, batch, pacc, pden, N);
    pool_fin_kernel<<<64, 64, 0, stream>>>(pacc, pden, out_W, out_b, out);
}

// Round 4
// 352.942 us; speedup vs baseline: 2.0407x; 1.1356x over previous
//
#include <hip/hip_runtime.h>
#include <hip/hip_bf16.h>

typedef unsigned short ushort_t;
typedef __attribute__((ext_vector_type(8))) short short8;
typedef __attribute__((ext_vector_type(4))) float float4v;

__device__ __forceinline__ float bfu_lo(unsigned u) {
    return __uint_as_float(u << 16);
}
__device__ __forceinline__ float bfu_hi(unsigned u) {
    return __uint_as_float(u & 0xffff0000u);
}
__device__ __forceinline__ ushort_t f2bf(float f) {
    __hip_bfloat16 h = __float2bfloat16(f);
    return *reinterpret_cast<ushort_t*>(&h);
}

// Wall layout per layer: 14 col-tiles (210 cols used), tile = 1024 ushorts:
//   idx = ct*1024 + kch*512 + lane*8 + j   (k = kch*32 + quad*8 + j, col = ct*16 + nn)
// cols: 0..127 qk2 (composed 0.125*Wq·Wk^T) | 128..191 skip | 192..209 qc (composed ea)

// ---------------- fused setup ----------------

__global__ __launch_bounds__(256) void setup_kernel(
    const float* __restrict__ x, const float* __restrict__ node_W,
    const float* __restrict__ node_b,
    const float* __restrict__ edge_W, const float* __restrict__ edge_b,
    const float* __restrict__ We, const float* __restrict__ be,
    const float* __restrict__ Wq, const float* __restrict__ bq,
    const float* __restrict__ Wk, const float* __restrict__ bk,
    const float* __restrict__ Wv, const float* __restrict__ bv,
    const float* __restrict__ Wskip, const float* __restrict__ bskip,
    float* __restrict__ h, ushort_t* __restrict__ h_bf,
    int* __restrict__ counts,
    float* __restrict__ Wc, float* __restrict__ bcb,
    ushort_t* __restrict__ Wall_arr, float* __restrict__ Wall_bias,
    ushort_t* __restrict__ wv_arr,
    int O0, int O1, int O2, int N) {
    int b = blockIdx.x, t = threadIdx.x;
    if (b < O0) {
        int idx = b * 256 + t;
        if (idx < N * 64) {
            int n = idx >> 6, c = idx & 63;
            float acc = node_b[c];
#pragma unroll
            for (int j = 0; j < 16; ++j) acc += x[n * 16 + j] * node_W[j * 64 + c];
            h[idx] = acc;
            h_bf[idx] = f2bf(acc);
        }
    } else if (b < O1) {
        int i = (b - O0) * 256 + t;
        if (i < N) counts[i] = 0;
    } else if (b < O2) {
        int tid = (b - O1) * 256 + t;
        if (tid < 2048) {
            int l = tid >> 10, d = (tid >> 7) & 7, j = tid & 127;
            float s = 0.f;
            for (int m = 0; m < 64; ++m) s += edge_W[d * 64 + m] * We[l * 8192 + m * 128 + j];
            Wc[l * 1024 + d * 128 + j] = s;
        } else if (tid < 2048 + 256) {
            int u = tid - 2048;
            int l = u >> 7, j = u & 127;
            float s = be[l * 128 + j];
            for (int m = 0; m < 64; ++m) s += edge_b[m] * We[l * 8192 + m * 128 + j];
            bcb[l * 128 + j] = s;
        }
    } else {
        int tid = (b - O2) * 256 + t;
        if (tid < 2 * 14336) {
            int l = tid / 14336, u = tid % 14336;
            int j = u & 7, ln = (u >> 3) & 63, kch = (u >> 9) & 1, ct = u >> 10;
            int nn = ln & 15, quad = ln >> 4;
            int k = kch * 32 + quad * 8 + j;
            int col = ct * 16 + nn;
            float v = 0.f;
            if (col < 128) {
                // composed 0.125 * (Wq_h Wk_h^T)[k, m]
                int hh = col >> 6, m = col & 63;
                const float* wq = Wq + l * 8192 + k * 128 + hh * 64;
                const float* wk = Wk + l * 8192 + m * 128 + hh * 64;
                float s = 0.f;
                for (int c2 = 0; c2 < 64; ++c2) s += wq[c2] * wk[c2];
                v = 0.125f * s;
            } else if (col < 192) {
                v = Wskip[l * 4096 + k * 64 + (col - 128)];
            }  // cols 192..223: 0 here; combine2 fills 192..209
            Wall_arr[(size_t)l * 14336 + ct * 1024 + kch * 512 + ln * 8 + j] = f2bf(v);
        } else if (tid < 2 * 14336 + 2 * 224) {
            int u = tid - 2 * 14336;
            int l = u / 224, col = u % 224;
            float v = 0.f;
            if (col < 128) {
                int hh = col >> 6, m = col & 63;
                const float* bqp = bq + l * 128 + hh * 64;
                const float* wk = Wk + l * 8192 + m * 128 + hh * 64;
                float s = 0.f;
                for (int c2 = 0; c2 < 64; ++c2) s += bqp[c2] * wk[c2];
                v = 0.125f * s;
            } else if (col < 192) {
                v = bskip[l * 64 + col - 128];
            }
            Wall_bias[l * 224 + col] = v;
        } else if (tid < 2 * 14336 + 2 * 224 + 2 * 8192) {
            // Wv stacked tiles: B[p = h*64+m][c] = Wv[m, h*64+c]
            // flat r = kc*2048 + ct*512 + ln*8 + j
            int u = tid - (2 * 14336 + 2 * 224);
            int l = u >> 13, r = u & 8191;
            int j = r & 7, ln = (r >> 3) & 63, ct = (r >> 9) & 3, kc = r >> 11;
            int quad = ln >> 4, nn = ln & 15;
            int p = kc * 32 + quad * 8 + j;
            int hh = p >> 6, m = p & 63;
            int c2 = ct * 16 + nn;
            wv_arr[(size_t)l * 8192 + r] = f2bf(Wv[l * 8192 + m * 128 + hh * 64 + c2]);
        }
    }
}

// combine2: qc composed columns (ea-dot path, with q·bk folded into bias cols) + cst
__global__ void combine2_kernel(const float* __restrict__ Wq, const float* __restrict__ bq,
                                const float* __restrict__ bk, const float* __restrict__ bv,
                                const float* __restrict__ Wc, const float* __restrict__ bcb,
                                ushort_t* __restrict__ Wall_arr, float* __restrict__ Wall_bias,
                                float* __restrict__ cst) {
    int tid = blockIdx.x * 256 + threadIdx.x;
    if (tid < 2304) {
        int l = tid / 1152, u = tid % 1152, k = u / 18, j = u % 18;
        float s = 0.f;
        if (j < 16) {
            int hh = j >> 3, d = j & 7;
            for (int c = 0; c < 64; ++c)
                s += Wq[l * 8192 + k * 128 + hh * 64 + c] * Wc[l * 1024 + d * 128 + hh * 64 + c];
        } else {
            int hh = j - 16;
            for (int c = 0; c < 64; ++c)
                s += Wq[l * 8192 + k * 128 + hh * 64 + c] *
                     (bcb[l * 128 + hh * 64 + c] + bk[l * 128 + hh * 64 + c]);
        }
        s *= 0.125f;
        int col = 192 + j;
        int ct = col >> 4, nn = col & 15;
        int kch = k >> 5, quad = (k >> 3) & 3, jj = k & 7;
        int ln = quad * 16 + nn;
        Wall_arr[(size_t)l * 14336 + ct * 1024 + kch * 512 + ln * 8 + jj] = f2bf(s);
    } else if (tid < 2304 + 36) {
        int u = tid - 2304;
        int l = u / 18, j = u % 18;
        float s = 0.f;
        if (j < 16) {
            int hh = j >> 3, d = j & 7;
            for (int c = 0; c < 64; ++c)
                s += bq[l * 128 + hh * 64 + c] * Wc[l * 1024 + d * 128 + hh * 64 + c];
        } else {
            int hh = j - 16;
            for (int c = 0; c < 64; ++c)
                s += bq[l * 128 + hh * 64 + c] *
                     (bcb[l * 128 + hh * 64 + c] + bk[l * 128 + hh * 64 + c]);
        }
        Wall_bias[l * 224 + 192 + j] = 0.125f * s;
    } else if (tid < 2304 + 36 + 128) {
        int u = tid - 2340;
        int l = u >> 6, c = u & 63;
        cst[l * 64 + c] = 0.5f * (bv[l * 128 + c] + bv[l * 128 + 64 + c] +
                                  bcb[l * 128 + c] + bcb[l * 128 + 64 + c]);
    }
}

// ---------------- CSR build ----------------

__global__ void csr_count_kernel(const int* __restrict__ dst, int* __restrict__ counts, int E) {
    int e = blockIdx.x * 256 + threadIdx.x;
    if (e < E) atomicAdd(&counts[dst[e]], 1);
}

__global__ void scan1_kernel(const int* __restrict__ counts, int* __restrict__ rowptr,
                             int* __restrict__ bsums, int N) {
    __shared__ int s[256];
    int t = threadIdx.x, i = blockIdx.x * 256 + t;
    int v = (i < N) ? counts[i] : 0;
    s[t] = v;
    __syncthreads();
    for (int d = 1; d < 256; d <<= 1) {
        int x = (t >= d) ? s[t - d] : 0;
        __syncthreads();
        s[t] += x;
        __syncthreads();
    }
    if (i < N) rowptr[i] = s[t] - v;
    if (t == 255) bsums[blockIdx.x] = s[255];
}

__global__ void scan3_kernel(int* __restrict__ rowptr, const int* __restrict__ bsums,
                             int* __restrict__ cursor, int N, int E, int nb) {
    __shared__ int sh[256];
    int t = threadIdx.x;
    int v = (t < nb) ? bsums[t] : 0;
    sh[t] = v;
    __syncthreads();
    for (int d = 1; d < 256; d <<= 1) {
        int x = (t >= d) ? sh[t - d] : 0;
        __syncthreads();
        sh[t] += x;
        __syncthreads();
    }
    int blk = blockIdx.x;
    int offv = (blk == 0) ? 0 : sh[blk - 1];
    int i = blk * 256 + t;
    if (i < N) {
        int r = rowptr[i] + offv;
        rowptr[i] = r;
        cursor[i] = r;
    }
    if (i == 0) rowptr[N] = E;
}

__global__ void csr_fill_kernel(const int* __restrict__ dst, const int* __restrict__ src,
                                const float* __restrict__ edge_attr, int* __restrict__ cursor,
                                int* __restrict__ csr_src, float* __restrict__ ea_perm, int E) {
    int e = blockIdx.x * 256 + threadIdx.x;
    if (e < E) {
        int pos = atomicAdd(&cursor[dst[e]], 1);
        csr_src[pos] = src[e] * 128;   // byte offset into h_bf (64 ch * 2B)
        float4 a0 = *(const float4*)(edge_attr + (size_t)e * 8);
        float4 a1 = *(const float4*)(edge_attr + (size_t)e * 8 + 4);
        *(float4*)(ea_perm + (size_t)pos * 8) = a0;
        *(float4*)(ea_perm + (size_t)pos * 8 + 4) = a1;
    }
}

// ---------------- per-layer MFMA GEMM: [32 x 64] @ [64 x 210] (from global h_bf) ----

__device__ __forceinline__ void gemm_store(
    int col, float bias, float4v c, int nbase, int N,
    ushort_t* __restrict__ qk2buf, float* __restrict__ outbuf, float* __restrict__ qcbuf) {
    if (col < 128) {
        ushort_t* qp = qk2buf + (size_t)nbase * 128 + col;
#pragma unroll
        for (int r = 0; r < 4; ++r)
            if (nbase + r < N) qp[(size_t)r * 128] = f2bf(c[r] + bias);
    } else if (col < 192) {
        float* op = outbuf + (size_t)nbase * 64 + (col - 128);
#pragma unroll
        for (int r = 0; r < 4; ++r)
            if (nbase + r < N) op[(size_t)r * 64] = c[r] + bias;
    } else if (col < 210) {
        float* qp2 = qcbuf + (size_t)nbase * 20 + (col - 192);
#pragma unroll
        for (int r = 0; r < 4; ++r)
            if (nbase + r < N) qp2[(size_t)r * 20] = c[r] + bias;
    }
}

__global__ __launch_bounds__(256) void qkv_mfma_kernel(
    const ushort_t* __restrict__ h_bf,
    const ushort_t* __restrict__ Wall_arr, const float* __restrict__ Wall_bias,
    ushort_t* __restrict__ qk2buf, float* __restrict__ outbuf, float* __restrict__ qcbuf,
    int N) {
    int wave = threadIdx.x >> 6, lane = threadIdx.x & 63;
    int quad = lane >> 4, nn = lane & 15;
    int n0 = blockIdx.x * 32;
    int nodeA = n0 + nn;       if (nodeA >= N) nodeA = N - 1;
    int nodeB = n0 + 16 + nn;  if (nodeB >= N) nodeB = N - 1;
    const ushort_t* apA = h_bf + (size_t)nodeA * 64 + quad * 8;
    const ushort_t* apB = h_bf + (size_t)nodeB * 64 + quad * 8;
    short8 aA0 = *(const short8*)apA;
    short8 aA1 = *(const short8*)(apA + 32);
    short8 aB0 = *(const short8*)apB;
    short8 aB1 = *(const short8*)(apB + 32);
    int ct_start = (wave < 2) ? wave * 4 : (8 + (wave - 2) * 3);
    int ct_cnt = (wave < 2) ? 4 : 3;
    for (int i = 0; i < ct_cnt; ++i) {
        int ct = ct_start + i;
        const ushort_t* bp = Wall_arr + (size_t)ct * 1024 + lane * 8;
        short8 b0 = *(const short8*)bp;
        short8 b1 = *(const short8*)(bp + 512);
        float4v cA = {0.f, 0.f, 0.f, 0.f};
        float4v cB = {0.f, 0.f, 0.f, 0.f};
        cA = __builtin_amdgcn_mfma_f32_16x16x32_bf16(aA0, b0, cA, 0, 0, 0);
        cA = __builtin_amdgcn_mfma_f32_16x16x32_bf16(aA1, b1, cA, 0, 0, 0);
        cB = __builtin_amdgcn_mfma_f32_16x16x32_bf16(aB0, b0, cB, 0, 0, 0);
        cB = __builtin_amdgcn_mfma_f32_16x16x32_bf16(aB1, b1, cB, 0, 0, 0);
        int col = ct * 16 + nn;
        float bias = Wall_bias[col];
        gemm_store(col, bias, cA, n0 + quad * 4, N, qk2buf, outbuf, qcbuf);
        gemm_store(col, bias, cB, n0 + 16 + quad * 4, N, qk2buf, outbuf, qcbuf);
    }
}

// ---------------- fused BN-apply(l) + GEMM(l+1): 32 nodes/block ----------------

__global__ __launch_bounds__(256) void bnqkv_kernel(
    const float* __restrict__ outbuf_in, const float* __restrict__ bnsums,
    const float* __restrict__ gamma, const float* __restrict__ beta,
    float* __restrict__ h, ushort_t* __restrict__ h_bf,
    const ushort_t* __restrict__ Wall_arr, const float* __restrict__ Wall_bias,
    ushort_t* __restrict__ qk2buf, float* __restrict__ outbuf, float* __restrict__ qcbuf,
    int N) {
    __shared__ ushort_t hb[32 * 64];
    __shared__ float ss_scale[64], ss_shift[64];
    int t = threadIdx.x;
    if (t < 64) {
        float invN = 1.f / (float)N;
        float mean = bnsums[t] * invN;
        float var = bnsums[64 + t] * invN - mean * mean;
        float sc = gamma[t] * rsqrtf(var + 1e-5f);
        ss_scale[t] = sc;
        ss_shift[t] = beta[t] - mean * sc;
    }
    __syncthreads();
    int n0 = blockIdx.x * 32;
    int c = t & 63;
    float sc = ss_scale[c], sh = ss_shift[c];
#pragma unroll
    for (int i = 0; i < 8; ++i) {
        int li = t + i * 256;
        int gidx = n0 * 64 + li;
        float hn = 0.f;
        if (gidx < N * 64) {
            float o = outbuf_in[gidx] * sc + sh;
            o = (o > 0.f) ? o : 0.01f * o;
            hn = h[gidx] + o;
            h[gidx] = hn;
            h_bf[gidx] = f2bf(hn);   // gather target for next attn layer
        }
        hb[li] = f2bf(hn);
    }
    __syncthreads();
    int wave = t >> 6, lane = t & 63;
    int quad = lane >> 4, nn = lane & 15;
    const ushort_t* apA = hb + nn * 64 + quad * 8;
    const ushort_t* apB = hb + (16 + nn) * 64 + quad * 8;
    short8 aA0 = *(const short8*)apA;
    short8 aA1 = *(const short8*)(apA + 32);
    short8 aB0 = *(const short8*)apB;
    short8 aB1 = *(const short8*)(apB + 32);
    int ct_start = (wave < 2) ? wave * 4 : (8 + (wave - 2) * 3);
    int ct_cnt = (wave < 2) ? 4 : 3;
    for (int i = 0; i < ct_cnt; ++i) {
        int ct = ct_start + i;
        const ushort_t* bp = Wall_arr + (size_t)ct * 1024 + lane * 8;
        short8 b0 = *(const short8*)bp;
        short8 b1 = *(const short8*)(bp + 512);
        float4v cA = {0.f, 0.f, 0.f, 0.f};
        float4v cB = {0.f, 0.f, 0.f, 0.f};
        cA = __builtin_amdgcn_mfma_f32_16x16x32_bf16(aA0, b0, cA, 0, 0, 0);
        cA = __builtin_amdgcn_mfma_f32_16x16x32_bf16(aA1, b1, cA, 0, 0, 0);
        cB = __builtin_amdgcn_mfma_f32_16x16x32_bf16(aB0, b0, cB, 0, 0, 0);
        cB = __builtin_amdgcn_mfma_f32_16x16x32_bf16(aB1, b1, cB, 0, 0, 0);
        int col = ct * 16 + nn;
        float bias = Wall_bias[col];
        gemm_store(col, bias, cA, n0 + quad * 4, N, qk2buf, outbuf, qcbuf);
        gemm_store(col, bias, cB, n0 + 16 + quad * 4, N, qk2buf, outbuf, qcbuf);
    }
}

// ---------------- attention: gather h_src only (128B/edge) ----------------
// 16-lane node groups, 4 nodes/wave, 16 nodes/block.
// lane l16: head = l16>>3, l8 = l16&7 holds h_src channels 8*l8..8*l8+7.
// logits = qk2[dst]·h_src + qc·ea + qb   (all 0.125-scaled at compose time)
// accumulates hacc = sum p*h_src (per head) and se = sum p*ea; V applied later.

__global__ __launch_bounds__(256) void attn_kernel(
    const ushort_t* __restrict__ h_bf, const ushort_t* __restrict__ qk2buf,
    const float* __restrict__ qcbuf,
    const int* __restrict__ csr_src, const float* __restrict__ ea_perm,
    const int* __restrict__ rowptr,
    ushort_t* __restrict__ haccn, float* __restrict__ sen, float* __restrict__ degw,
    int N) {
    int t = threadIdx.x;
    int lane = t & 63, wid = t >> 6;
    int grp = lane >> 4, l16 = lane & 15;
    int head = l16 >> 3, l8 = l16 & 7;
    const char* hbb = (const char*)h_bf;

    int n = blockIdx.x * 16 + wid * 4 + grp;
    bool active = (n < N);
    int nn = active ? n : (N - 1);
    int start = rowptr[nn];
    int deg = active ? (rowptr[nn + 1] - start) : 0;
    int wdeg = deg;
    wdeg = max(wdeg, __shfl_xor(wdeg, 16));
    wdeg = max(wdeg, __shfl_xor(wdeg, 32));

    float lsum = 0.f;
    float hacc[8] = {0.f, 0.f, 0.f, 0.f, 0.f, 0.f, 0.f, 0.f};
    float se[8]   = {0.f, 0.f, 0.f, 0.f, 0.f, 0.f, 0.f, 0.f};

    if (wdeg > 0) {
        // qk2 fragment: 8 channels of the dst node's composed query (this head)
        uint4 qr = *(const uint4*)((const char*)qk2buf + (size_t)nn * 256 + head * 128 + l8 * 16);
        float qk0 = bfu_lo(qr.x), qk1 = bfu_hi(qr.x);
        float qk2f = bfu_lo(qr.y), qk3 = bfu_hi(qr.y);
        float qk4 = bfu_lo(qr.z), qk5 = bfu_hi(qr.z);
        float qk6 = bfu_lo(qr.w), qk7 = bfu_hi(qr.w);
        const float* qcp = qcbuf + (size_t)nn * 20;
        float4 qcA = *(const float4*)(qcp + head * 8);
        float4 qcB = *(const float4*)(qcp + head * 8 + 4);
        float qb = qcp[16 + head];

        bool dpos = (deg > 0);
        int dclamp = dpos ? (deg - 1) : 0;

        int offL = csr_src[dpos ? (start + min(l16, dclamp)) : 0];
        int o0 = __shfl(offL, grp * 16);
        uint4 ca = *(const uint4*)(hbb + (size_t)(unsigned)o0 + l8 * 16);
        int gi0 = dpos ? start : 0;
        float4 e0 = *(const float4*)(ea_perm + (size_t)gi0 * 8);
        float4 e1 = *(const float4*)(ea_perm + (size_t)gi0 * 8 + 4);

        for (int it = 0; it < wdeg; ++it) {
            int itn = it + 1;
            if ((itn & 15) == 0)
                offL = csr_src[dpos ? (start + min(itn + l16, dclamp)) : 0];
            int itc = min(itn, wdeg - 1);
            int on = __shfl(offL, grp * 16 + (itc & 15));
            uint4 na = *(const uint4*)(hbb + (size_t)(unsigned)on + l8 * 16);
            int gin = dpos ? (start + min(itc, dclamp)) : 0;
            float4 f0 = *(const float4*)(ea_perm + (size_t)gin * 8);
            float4 f1 = *(const float4*)(ea_perm + (size_t)gin * 8 + 4);

            float h0 = bfu_lo(ca.x), h1 = bfu_hi(ca.x);
            float h2 = bfu_lo(ca.y), h3 = bfu_hi(ca.y);
            float h4 = bfu_lo(ca.z), h5 = bfu_hi(ca.z);
            float h6 = bfu_lo(ca.w), h7 = bfu_hi(ca.w);
            float dt = qk0 * h0 + qk1 * h1 + qk2f * h2 + qk3 * h3
                     + qk4 * h4 + qk5 * h5 + qk6 * h6 + qk7 * h7;
            dt += __shfl_xor(dt, 1);
            dt += __shfl_xor(dt, 2);
            dt += __shfl_xor(dt, 4);
            float s0 = dt
                     + qcA.x * e0.x + qcA.y * e0.y + qcA.z * e0.z + qcA.w * e0.w
                     + qcB.x * e1.x + qcB.y * e1.y + qcB.z * e1.z + qcB.w * e1.w
                     + qb;
            float p = (it < deg) ? __expf(fmaxf(s0, -60.f)) : 0.f;
            lsum += p;
            hacc[0] += p * h0; hacc[1] += p * h1;
            hacc[2] += p * h2; hacc[3] += p * h3;
            hacc[4] += p * h4; hacc[5] += p * h5;
            hacc[6] += p * h6; hacc[7] += p * h7;
            se[0] += p * e0.x; se[1] += p * e0.y; se[2] += p * e0.z; se[3] += p * e0.w;
            se[4] += p * e1.x; se[5] += p * e1.y; se[6] += p * e1.z; se[7] += p * e1.w;
            ca = na; e0 = f0; e1 = f1;
        }
    }

    if (active) {
        float inv = (deg > 0) ? (0.5f / lsum) : 0.f;   // 0.5 = head mean
        unsigned pw0 = (unsigned)f2bf(hacc[0] * inv) | ((unsigned)f2bf(hacc[1] * inv) << 16);
        unsigned pw1 = (unsigned)f2bf(hacc[2] * inv) | ((unsigned)f2bf(hacc[3] * inv) << 16);
        unsigned pw2 = (unsigned)f2bf(hacc[4] * inv) | ((unsigned)f2bf(hacc[5] * inv) << 16);
        unsigned pw3 = (unsigned)f2bf(hacc[6] * inv) | ((unsigned)f2bf(hacc[7] * inv) << 16);
        uint4 pk = make_uint4(pw0, pw1, pw2, pw3);
        *(uint4*)((char*)haccn + (size_t)nn * 256 + head * 128 + l8 * 16) = pk;
        if (l8 == 0) {
            *(float4*)(sen + (size_t)nn * 16 + head * 8) =
                make_float4(se[0] * inv, se[1] * inv, se[2] * inv, se[3] * inv);
            *(float4*)(sen + (size_t)nn * 16 + head * 8 + 4) =
                make_float4(se[4] * inv, se[5] * inv, se[6] * inv, se[7] * inv);
            if (head == 0) degw[nn] = (deg > 0) ? 1.f : 0.f;
        }
    }
}

// ---------------- vapply: out = haccn @ Wv_stk + ep-compose + cst + skip; BN partials --

__global__ __launch_bounds__(256) void vapply_kernel(
    const ushort_t* __restrict__ haccn, const float* __restrict__ sen,
    const float* __restrict__ degw,
    const ushort_t* __restrict__ wv_arr, const float* __restrict__ Wc,
    const float* __restrict__ cst,
    float* __restrict__ outbuf, float* __restrict__ part, int N) {
    __shared__ float Wc_s[1024];
    __shared__ float cst_s[64];
    __shared__ float sen_s[32][16];
    __shared__ float dw_s[32];
    __shared__ float ps[128];
    int t = threadIdx.x;
    for (int i = t; i < 1024; i += 256) Wc_s[i] = Wc[i];
    if (t < 64) cst_s[t] = cst[t];
    int n0 = blockIdx.x * 32;
    for (int i = t; i < 512; i += 256) {
        int ln2 = i >> 4;
        int nc = n0 + ln2; if (nc >= N) nc = N - 1;
        sen_s[ln2][i & 15] = sen[(size_t)nc * 16 + (i & 15)];
    }
    if (t < 32) {
        int nc = n0 + t; if (nc >= N) nc = N - 1;
        dw_s[t] = degw[nc];
    }
    __syncthreads();
    int wave = t >> 6, lane = t & 63;
    int quad = lane >> 4, nn = lane & 15;
    int nodeA = n0 + nn;       if (nodeA >= N) nodeA = N - 1;
    int nodeB = n0 + 16 + nn;  if (nodeB >= N) nodeB = N - 1;
    int ct = wave;
    float4v cA = {0.f, 0.f, 0.f, 0.f};
    float4v cB = {0.f, 0.f, 0.f, 0.f};
#pragma unroll
    for (int kc = 0; kc < 4; ++kc) {
        short8 aA = *(const short8*)(haccn + (size_t)nodeA * 128 + kc * 32 + quad * 8);
        short8 aB = *(const short8*)(haccn + (size_t)nodeB * 128 + kc * 32 + quad * 8);
        short8 bb = *(const short8*)(wv_arr + kc * 2048 + ct * 512 + lane * 8);
        cA = __builtin_amdgcn_mfma_f32_16x16x32_bf16(aA, bb, cA, 0, 0, 0);
        cB = __builtin_amdgcn_mfma_f32_16x16x32_bf16(aB, bb, cB, 0, 0, 0);
    }
    int col = ct * 16 + nn;
    float sa = 0.f, sq = 0.f;
#pragma unroll
    for (int g = 0; g < 2; ++g) {
        float4v acc = g ? cB : cA;
        int lbase = g * 16 + quad * 4;
#pragma unroll
        for (int r = 0; r < 4; ++r) {
            int ln2 = lbase + r;
            int nr = n0 + ln2;
            const float* sp = sen_s[ln2];
            float ep = 0.f;
#pragma unroll
            for (int hh = 0; hh < 2; ++hh)
#pragma unroll
                for (int d = 0; d < 8; ++d)
                    ep += sp[hh * 8 + d] * Wc_s[d * 128 + hh * 64 + col];
            if (nr < N) {
                float val = acc[r] + ep + dw_s[ln2] * cst_s[col] +
                            outbuf[(size_t)nr * 64 + col];
                outbuf[(size_t)nr * 64 + col] = val;
                sa += val;
                sq += val * val;
            }
        }
    }
    sa += __shfl_xor(sa, 16); sa += __shfl_xor(sa, 32);
    sq += __shfl_xor(sq, 16); sq += __shfl_xor(sq, 32);
    if (quad == 0) { ps[col] = sa; ps[64 + col] = sq; }
    __syncthreads();
    if (t < 128) part[(size_t)blockIdx.x * 128 + t] = ps[t];
}

// ---------------- BN reduce + final-layer apply w/ gate ----------------

__global__ __launch_bounds__(256) void bnreduce_kernel(const float* __restrict__ part,
                                                       float* __restrict__ bnsums, int nb) {
    int s = blockIdx.x;  // 0..127
    int t = threadIdx.x;
    float a = 0.f;
    for (int b = t; b < nb; b += 256) a += part[(size_t)b * 128 + s];
    __shared__ float sh[256];
    sh[t] = a;
    __syncthreads();
    for (int d = 128; d; d >>= 1) {
        if (t < d) sh[t] += sh[t + d];
        __syncthreads();
    }
    if (t == 0) bnsums[s] = sh[0];
}

__global__ __launch_bounds__(256) void bnapply_kernel(
    const float* __restrict__ outbuf, const float* __restrict__ bnsums,
    const float* __restrict__ gamma, const float* __restrict__ beta,
    const float* __restrict__ gate_W, const float* __restrict__ gate_b,
    float* __restrict__ h, float* __restrict__ gatebuf, int N) {
    int idx = blockIdx.x * 256 + threadIdx.x;
    if (idx >= N * 64) return;
    int c = idx & 63, n = idx >> 6;
    float invN = 1.f / (float)N;
    float mean = bnsums[c] * invN;
    float var = bnsums[64 + c] * invN - mean * mean;
    float scale = gamma[c] * rsqrtf(var + 1e-5f);
    float shift = beta[c] - mean * scale;
    float o = outbuf[idx] * scale + shift;
    o = (o > 0.f) ? o : 0.01f * o;
    float hn = h[idx] + o;
    h[idx] = hn;
    float g = hn * gate_W[c];
#pragma unroll
    for (int off = 32; off; off >>= 1) g += __shfl_xor(g, off);
    if (c == 0) gatebuf[n] = g + gate_b[0];
}

// ---------------- pooling (max fused into acc) ----------------

__global__ __launch_bounds__(256) void pool_acc_kernel(
    const float* __restrict__ h, const float* __restrict__ gatebuf,
    const int* __restrict__ batch,
    float* __restrict__ pacc, float* __restrict__ pden, int N) {
    int b = blockIdx.x >> 3, chunk = blockIdx.x & 7;
    int lo = 0, hi = N;
    while (lo < hi) { int mid = (lo + hi) >> 1; if (batch[mid] < b) lo = mid + 1; else hi = mid; }
    int start = lo;
    lo = start; hi = N;
    while (lo < hi) { int mid = (lo + hi) >> 1; if (batch[mid] <= b) lo = mid + 1; else hi = mid; }
    int end = lo;
    int t = threadIdx.x, lane = t & 63, wid = t >> 6;
    __shared__ float sm[4];
    float mx = -1e30f;
    for (int n = start + t; n < end; n += 256) mx = fmaxf(mx, gatebuf[n]);
#pragma unroll
    for (int off = 32; off; off >>= 1) mx = fmaxf(mx, __shfl_xor(mx, off));
    if (lane == 0) sm[wid] = mx;
    __syncthreads();
    float mb = fmaxf(fmaxf(sm[0], sm[1]), fmaxf(sm[2], sm[3]));
    int gwid = chunk * 4 + wid;
    float acc = 0.f, den = 0.f;
    for (int n = start + gwid; n < end; n += 32) {
        float ge = __expf(gatebuf[n] - mb);
        acc += ge * h[(size_t)n * 64 + lane];
        den += ge;
    }
    __shared__ float sacc[4][64];
    __shared__ float sden[4];
    sacc[wid][lane] = acc;
    if (lane == 0) sden[wid] = den;
    __syncthreads();
    if (wid == 0) {
        pacc[(size_t)blockIdx.x * 64 + lane] =
            sacc[0][lane] + sacc[1][lane] + sacc[2][lane] + sacc[3][lane];
        if (lane == 0) pden[blockIdx.x] = sden[0] + sden[1] + sden[2] + sden[3];
    }
}

__global__ void pool_fin_kernel(const float* __restrict__ pacc, const float* __restrict__ pden,
                                const float* __restrict__ out_W, const float* __restrict__ out_b,
                                float* __restrict__ out) {
    int b = blockIdx.x, c = threadIdx.x;
    float pc = 0.f, dv = 0.f;
#pragma unroll
    for (int j = 0; j < 8; ++j) {
        pc += pacc[(size_t)(b * 8 + j) * 64 + c];
        dv += pden[b * 8 + j];
    }
    float s = pc * out_W[c];
#pragma unroll
    for (int off = 32; off; off >>= 1) s += __shfl_xor(s, off);
    if (c == 0) {
        if (dv <= 0.f) dv = 1.f;
        float v = s / dv + out_b[0];
        out[b] = 1.f / (1.f + __expf(-v));
    }
}

// ---------------- host ----------------

extern "C" void kernel_launch(void* const* d_in, const int* in_sizes, int n_in,
                              void* d_out, int out_size, void* d_ws, size_t ws_size,
                              hipStream_t stream) {
    const float* x         = (const float*)d_in[0];
    const float* edge_attr = (const float*)d_in[1];
    const int*   edge_src  = (const int*)d_in[2];
    const int*   edge_dst  = (const int*)d_in[3];
    const int*   batch     = (const int*)d_in[4];
    const float* node_W    = (const float*)d_in[5];
    const float* node_b    = (const float*)d_in[6];
    const float* edge_W    = (const float*)d_in[7];
    const float* edge_b    = (const float*)d_in[8];
    const float* Wq        = (const float*)d_in[9];
    const float* bq        = (const float*)d_in[10];
    const float* Wk        = (const float*)d_in[11];
    const float* bk        = (const float*)d_in[12];
    const float* Wv        = (const float*)d_in[13];
    const float* bv        = (const float*)d_in[14];
    const float* We        = (const float*)d_in[15];
    const float* be        = (const float*)d_in[16];
    const float* Wskip     = (const float*)d_in[17];
    const float* bskip     = (const float*)d_in[18];
    const float* gamma     = (const float*)d_in[19];
    const float* beta      = (const float*)d_in[20];
    const float* gate_W    = (const float*)d_in[21];
    const float* gate_b    = (const float*)d_in[22];
    const float* out_W     = (const float*)d_in[23];
    const float* out_b     = (const float*)d_in[24];
    float* out = (float*)d_out;

    const int N = in_sizes[0] / 16;
    const int E = in_sizes[2];
    const int nba = (N + 15) / 16;   // attn blocks: 16 nodes per block
    const int nbv = (N + 31) / 32;   // vapply / gemm blocks: 32 nodes per block

    char* ws = (char*)d_ws;
    size_t off = 0;
    auto alloc = [&](size_t bytes) {
        size_t o = off;
        off += (bytes + 255) & ~(size_t)255;
        return o;
    };
    float*    h        = (float*)(ws + alloc((size_t)N * 64 * 4));
    ushort_t* h_bf     = (ushort_t*)(ws + alloc((size_t)N * 64 * 2));
    ushort_t* qk2buf   = (ushort_t*)(ws + alloc((size_t)N * 128 * 2));
    float*    outbuf   = (float*)(ws + alloc((size_t)N * 64 * 4));
    float*    qcbuf    = (float*)(ws + alloc((size_t)N * 20 * 4));
    ushort_t* haccn    = (ushort_t*)(ws + alloc((size_t)N * 128 * 2));
    float*    sen      = (float*)(ws + alloc((size_t)N * 16 * 4));
    float*    degw     = (float*)(ws + alloc((size_t)N * 4));
    int*      rowptr   = (int*)(ws + alloc((size_t)(N + 1) * 4));
    int*      cursor   = (int*)(ws + alloc((size_t)N * 4));
    int*      counts   = (int*)(ws + alloc((size_t)N * 4));
    int*      bsums    = (int*)(ws + alloc(1024));
    int*      csr_src  = (int*)(ws + alloc((size_t)E * 4));
    float*    ea_perm  = (float*)(ws + alloc((size_t)E * 8 * 4));
    float*    Wc       = (float*)(ws + alloc(2 * 1024 * 4));
    float*    bcb      = (float*)(ws + alloc(2 * 128 * 4));
    ushort_t* Wall_arr = (ushort_t*)(ws + alloc(2 * 14336 * 2));
    float*    Wall_b   = (float*)(ws + alloc(2 * 224 * 4));
    ushort_t* wv_arr   = (ushort_t*)(ws + alloc(2 * 8192 * 2));
    float*    cst      = (float*)(ws + alloc(2 * 64 * 4));
    float*    bnsums   = (float*)(ws + alloc(128 * 4));
    float*    gatebuf  = (float*)(ws + alloc((size_t)N * 4));
    float*    part     = (float*)(ws + alloc((size_t)nbv * 128 * 4));
    float*    pacc     = (float*)(ws + alloc((size_t)512 * 64 * 4));
    float*    pden     = (float*)(ws + alloc(512 * 4));
    if (off > ws_size) return;

    int O0 = (N * 64 + 255) / 256;
    int O1 = O0 + (N + 255) / 256;
    int O2 = O1 + 9;
    int O3 = O2 + 178;   // 2*14336 + 2*224 + 2*8192 = 45504 -> 178 blocks
    setup_kernel<<<O3, 256, 0, stream>>>(
        x, node_W, node_b, edge_W, edge_b, We, be, Wq, bq, Wk, bk, Wv, bv, Wskip, bskip,
        h, h_bf, counts, Wc, bcb, Wall_arr, Wall_b, wv_arr, O0, O1, O2, N);
    combine2_kernel<<<10, 256, 0, stream>>>(Wq, bq, bk, bv, Wc, bcb, Wall_arr, Wall_b, cst);

    csr_count_kernel<<<(E + 255) / 256, 256, 0, stream>>>(edge_dst, counts, E);
    int nb = (N + 255) / 256;
    scan1_kernel<<<nb, 256, 0, stream>>>(counts, rowptr, bsums, N);
    scan3_kernel<<<nb, 256, 0, stream>>>(rowptr, bsums, cursor, N, E, nb);
    csr_fill_kernel<<<(E + 255) / 256, 256, 0, stream>>>(edge_dst, edge_src, edge_attr,
                                                         cursor, csr_src, ea_perm, E);

    // layer 0
    qkv_mfma_kernel<<<nbv, 256, 0, stream>>>(
        h_bf, Wall_arr, Wall_b, qk2buf, outbuf, qcbuf, N);
    attn_kernel<<<nba, 256, 0, stream>>>(h_bf, qk2buf, qcbuf, csr_src, ea_perm,
                                         rowptr, haccn, sen, degw, N);
    vapply_kernel<<<nbv, 256, 0, stream>>>(haccn, sen, degw, wv_arr, Wc, cst,
                                           outbuf, part, N);
    bnreduce_kernel<<<128, 256, 0, stream>>>(part, bnsums, nbv);
    bnqkv_kernel<<<nbv, 256, 0, stream>>>(
        outbuf, bnsums, gamma, beta, h, h_bf,
        Wall_arr + 14336, Wall_b + 224, qk2buf, outbuf, qcbuf, N);

    // layer 1
    attn_kernel<<<nba, 256, 0, stream>>>(h_bf, qk2buf, qcbuf, csr_src, ea_perm,
                                         rowptr, haccn, sen, degw, N);
    vapply_kernel<<<nbv, 256, 0, stream>>>(haccn, sen, degw, wv_arr + 8192, Wc + 1024,
                                           cst + 64, outbuf, part, N);
    bnreduce_kernel<<<128, 256, 0, stream>>>(part, bnsums, nbv);
    bnapply_kernel<<<(N * 64 + 255) / 256, 256, 0, stream>>>(
        outbuf, bnsums, gamma + 64, beta + 64, gate_W, gate_b, h, gatebuf, N);

    pool_acc_kernel<<<512, 256, 0, stream>>>(h, gatebuf, batch, pacc, pden, N);
    pool_fin_kernel<<<64, 64, 0, stream>>>(pacc, pden, out_W, out_b, out);
}

// Round 5
// 349.368 us; speedup vs baseline: 2.0616x; 1.0102x over previous
//
#include <hip/hip_runtime.h>
#include <hip/hip_bf16.h>

typedef unsigned short ushort_t;
typedef __attribute__((ext_vector_type(8))) short short8;
typedef __attribute__((ext_vector_type(4))) float float4v;

__device__ __forceinline__ float bfu_lo(unsigned u) {
    return __uint_as_float(u << 16);
}
__device__ __forceinline__ float bfu_hi(unsigned u) {
    return __uint_as_float(u & 0xffff0000u);
}
__device__ __forceinline__ ushort_t f2bf(float f) {
    __hip_bfloat16 h = __float2bfloat16(f);
    return *reinterpret_cast<ushort_t*>(&h);
}

// Wall layout per layer: 14 col-tiles (210 cols used), tile = 1024 ushorts:
//   idx = ct*1024 + kch*512 + lane*8 + j   (k = kch*32 + quad*8 + j, col = ct*16 + nn)
// cols: 0..127 qk2 (composed 0.125*Wq·Wk^T) | 128..191 skip | 192..209 qc (composed ea)
// Edge record (32 B, sector-aligned): +0 src byte-offset (int), +16 ea bf16x8.

// ---------------- fused setup ----------------

__global__ __launch_bounds__(256) void setup_kernel(
    const float* __restrict__ x, const float* __restrict__ node_W,
    const float* __restrict__ node_b,
    const float* __restrict__ edge_W, const float* __restrict__ edge_b,
    const float* __restrict__ We, const float* __restrict__ be,
    const float* __restrict__ Wq, const float* __restrict__ bq,
    const float* __restrict__ Wk, const float* __restrict__ bk,
    const float* __restrict__ Wv, const float* __restrict__ bv,
    const float* __restrict__ Wskip, const float* __restrict__ bskip,
    float* __restrict__ h, ushort_t* __restrict__ h_bf,
    int* __restrict__ counts,
    float* __restrict__ Wc, float* __restrict__ bcb,
    ushort_t* __restrict__ Wall_arr, float* __restrict__ Wall_bias,
    ushort_t* __restrict__ wv_arr,
    int O0, int O1, int O2, int N) {
    int b = blockIdx.x, t = threadIdx.x;
    if (b < O0) {
        int idx = b * 256 + t;
        if (idx < N * 64) {
            int n = idx >> 6, c = idx & 63;
            float acc = node_b[c];
#pragma unroll
            for (int j = 0; j < 16; ++j) acc += x[n * 16 + j] * node_W[j * 64 + c];
            h[idx] = acc;
            h_bf[idx] = f2bf(acc);
        }
    } else if (b < O1) {
        int i = (b - O0) * 256 + t;
        if (i < N) counts[i] = 0;
    } else if (b < O2) {
        int tid = (b - O1) * 256 + t;
        if (tid < 2048) {
            int l = tid >> 10, d = (tid >> 7) & 7, j = tid & 127;
            float s = 0.f;
            for (int m = 0; m < 64; ++m) s += edge_W[d * 64 + m] * We[l * 8192 + m * 128 + j];
            Wc[l * 1024 + d * 128 + j] = s;
        } else if (tid < 2048 + 256) {
            int u = tid - 2048;
            int l = u >> 7, j = u & 127;
            float s = be[l * 128 + j];
            for (int m = 0; m < 64; ++m) s += edge_b[m] * We[l * 8192 + m * 128 + j];
            bcb[l * 128 + j] = s;
        }
    } else {
        int tid = (b - O2) * 256 + t;
        if (tid < 2 * 14336) {
            int l = tid / 14336, u = tid % 14336;
            int j = u & 7, ln = (u >> 3) & 63, kch = (u >> 9) & 1, ct = u >> 10;
            int nn = ln & 15, quad = ln >> 4;
            int k = kch * 32 + quad * 8 + j;
            int col = ct * 16 + nn;
            float v = 0.f;
            if (col < 128) {
                // composed 0.125 * (Wq_h Wk_h^T)[k, m]
                int hh = col >> 6, m = col & 63;
                const float* wq = Wq + l * 8192 + k * 128 + hh * 64;
                const float* wk = Wk + l * 8192 + m * 128 + hh * 64;
                float s = 0.f;
                for (int c2 = 0; c2 < 64; ++c2) s += wq[c2] * wk[c2];
                v = 0.125f * s;
            } else if (col < 192) {
                v = Wskip[l * 4096 + k * 64 + (col - 128)];
            }  // cols 192..223: 0 here; combine2 fills 192..209
            Wall_arr[(size_t)l * 14336 + ct * 1024 + kch * 512 + ln * 8 + j] = f2bf(v);
        } else if (tid < 2 * 14336 + 2 * 224) {
            int u = tid - 2 * 14336;
            int l = u / 224, col = u % 224;
            float v = 0.f;
            if (col < 128) {
                int hh = col >> 6, m = col & 63;
                const float* bqp = bq + l * 128 + hh * 64;
                const float* wk = Wk + l * 8192 + m * 128 + hh * 64;
                float s = 0.f;
                for (int c2 = 0; c2 < 64; ++c2) s += bqp[c2] * wk[c2];
                v = 0.125f * s;
            } else if (col < 192) {
                v = bskip[l * 64 + col - 128];
            }
            Wall_bias[l * 224 + col] = v;
        } else if (tid < 2 * 14336 + 2 * 224 + 2 * 8192) {
            // Wv stacked tiles: B[p = h*64+m][c] = Wv[m, h*64+c]
            // flat r = kc*2048 + ct*512 + ln*8 + j
            int u = tid - (2 * 14336 + 2 * 224);
            int l = u >> 13, r = u & 8191;
            int j = r & 7, ln = (r >> 3) & 63, ct = (r >> 9) & 3, kc = r >> 11;
            int quad = ln >> 4, nn = ln & 15;
            int p = kc * 32 + quad * 8 + j;
            int hh = p >> 6, m = p & 63;
            int c2 = ct * 16 + nn;
            wv_arr[(size_t)l * 8192 + r] = f2bf(Wv[l * 8192 + m * 128 + hh * 64 + c2]);
        }
    }
}

// combine2: qc composed columns (ea-dot path, with q·bk folded into bias cols) + cst
__global__ void combine2_kernel(const float* __restrict__ Wq, const float* __restrict__ bq,
                                const float* __restrict__ bk, const float* __restrict__ bv,
                                const float* __restrict__ Wc, const float* __restrict__ bcb,
                                ushort_t* __restrict__ Wall_arr, float* __restrict__ Wall_bias,
                                float* __restrict__ cst) {
    int tid = blockIdx.x * 256 + threadIdx.x;
    if (tid < 2304) {
        int l = tid / 1152, u = tid % 1152, k = u / 18, j = u % 18;
        float s = 0.f;
        if (j < 16) {
            int hh = j >> 3, d = j & 7;
            for (int c = 0; c < 64; ++c)
                s += Wq[l * 8192 + k * 128 + hh * 64 + c] * Wc[l * 1024 + d * 128 + hh * 64 + c];
        } else {
            int hh = j - 16;
            for (int c = 0; c < 64; ++c)
                s += Wq[l * 8192 + k * 128 + hh * 64 + c] *
                     (bcb[l * 128 + hh * 64 + c] + bk[l * 128 + hh * 64 + c]);
        }
        s *= 0.125f;
        int col = 192 + j;
        int ct = col >> 4, nn = col & 15;
        int kch = k >> 5, quad = (k >> 3) & 3, jj = k & 7;
        int ln = quad * 16 + nn;
        Wall_arr[(size_t)l * 14336 + ct * 1024 + kch * 512 + ln * 8 + jj] = f2bf(s);
    } else if (tid < 2304 + 36) {
        int u = tid - 2304;
        int l = u / 18, j = u % 18;
        float s = 0.f;
        if (j < 16) {
            int hh = j >> 3, d = j & 7;
            for (int c = 0; c < 64; ++c)
                s += bq[l * 128 + hh * 64 + c] * Wc[l * 1024 + d * 128 + hh * 64 + c];
        } else {
            int hh = j - 16;
            for (int c = 0; c < 64; ++c)
                s += bq[l * 128 + hh * 64 + c] *
                     (bcb[l * 128 + hh * 64 + c] + bk[l * 128 + hh * 64 + c]);
        }
        Wall_bias[l * 224 + 192 + j] = 0.125f * s;
    } else if (tid < 2304 + 36 + 128) {
        int u = tid - 2340;
        int l = u >> 6, c = u & 63;
        cst[l * 64 + c] = 0.5f * (bv[l * 128 + c] + bv[l * 128 + 64 + c] +
                                  bcb[l * 128 + c] + bcb[l * 128 + 64 + c]);
    }
}

// ---------------- CSR build ----------------

__global__ void csr_count_kernel(const int* __restrict__ dst, int* __restrict__ counts, int E) {
    int e = blockIdx.x * 256 + threadIdx.x;
    if (e < E) atomicAdd(&counts[dst[e]], 1);
}

__global__ void scan1_kernel(const int* __restrict__ counts, int* __restrict__ rowptr,
                             int* __restrict__ bsums, int N) {
    __shared__ int s[256];
    int t = threadIdx.x, i = blockIdx.x * 256 + t;
    int v = (i < N) ? counts[i] : 0;
    s[t] = v;
    __syncthreads();
    for (int d = 1; d < 256; d <<= 1) {
        int x = (t >= d) ? s[t - d] : 0;
        __syncthreads();
        s[t] += x;
        __syncthreads();
    }
    if (i < N) rowptr[i] = s[t] - v;
    if (t == 255) bsums[blockIdx.x] = s[255];
}

__global__ void scan3_kernel(int* __restrict__ rowptr, const int* __restrict__ bsums,
                             int* __restrict__ cursor, int N, int E, int nb) {
    __shared__ int sh[256];
    int t = threadIdx.x;
    int v = (t < nb) ? bsums[t] : 0;
    sh[t] = v;
    __syncthreads();
    for (int d = 1; d < 256; d <<= 1) {
        int x = (t >= d) ? sh[t - d] : 0;
        __syncthreads();
        sh[t] += x;
        __syncthreads();
    }
    int blk = blockIdx.x;
    int offv = (blk == 0) ? 0 : sh[blk - 1];
    int i = blk * 256 + t;
    if (i < N) {
        int r = rowptr[i] + offv;
        rowptr[i] = r;
        cursor[i] = r;
    }
    if (i == 0) rowptr[N] = E;
}

// one 32-B record per edge: [src_off:int | pad:12B | ea bf16x8:16B]
__global__ void csr_fill_kernel(const int* __restrict__ dst, const int* __restrict__ src,
                                const float* __restrict__ edge_attr, int* __restrict__ cursor,
                                char* __restrict__ erec, int E) {
    int e = blockIdx.x * 256 + threadIdx.x;
    if (e < E) {
        int pos = atomicAdd(&cursor[dst[e]], 1);
        float4 a0 = *(const float4*)(edge_attr + (size_t)e * 8);
        float4 a1 = *(const float4*)(edge_attr + (size_t)e * 8 + 4);
        uint4 w1;
        w1.x = (unsigned)f2bf(a0.x) | ((unsigned)f2bf(a0.y) << 16);
        w1.y = (unsigned)f2bf(a0.z) | ((unsigned)f2bf(a0.w) << 16);
        w1.z = (unsigned)f2bf(a1.x) | ((unsigned)f2bf(a1.y) << 16);
        w1.w = (unsigned)f2bf(a1.z) | ((unsigned)f2bf(a1.w) << 16);
        char* rp = erec + (size_t)pos * 32;
        *(uint4*)rp = make_uint4((unsigned)(src[e] * 128), 0u, 0u, 0u);
        *(uint4*)(rp + 16) = w1;
    }
}

// ---------------- per-layer MFMA GEMM: [32 x 64] @ [64 x 210] (from global h_bf) ----

__device__ __forceinline__ void gemm_store(
    int col, float bias, float4v c, int nbase, int N,
    ushort_t* __restrict__ qk2buf, float* __restrict__ outbuf, float* __restrict__ qcbuf) {
    if (col < 128) {
        ushort_t* qp = qk2buf + (size_t)nbase * 128 + col;
#pragma unroll
        for (int r = 0; r < 4; ++r)
            if (nbase + r < N) qp[(size_t)r * 128] = f2bf(c[r] + bias);
    } else if (col < 192) {
        float* op = outbuf + (size_t)nbase * 64 + (col - 128);
#pragma unroll
        for (int r = 0; r < 4; ++r)
            if (nbase + r < N) op[(size_t)r * 64] = c[r] + bias;
    } else if (col < 210) {
        float* qp2 = qcbuf + (size_t)nbase * 20 + (col - 192);
#pragma unroll
        for (int r = 0; r < 4; ++r)
            if (nbase + r < N) qp2[(size_t)r * 20] = c[r] + bias;
    }
}

__global__ __launch_bounds__(256) void qkv_mfma_kernel(
    const ushort_t* __restrict__ h_bf,
    const ushort_t* __restrict__ Wall_arr, const float* __restrict__ Wall_bias,
    ushort_t* __restrict__ qk2buf, float* __restrict__ outbuf, float* __restrict__ qcbuf,
    int N) {
    int wave = threadIdx.x >> 6, lane = threadIdx.x & 63;
    int quad = lane >> 4, nn = lane & 15;
    int n0 = blockIdx.x * 32;
    int nodeA = n0 + nn;       if (nodeA >= N) nodeA = N - 1;
    int nodeB = n0 + 16 + nn;  if (nodeB >= N) nodeB = N - 1;
    const ushort_t* apA = h_bf + (size_t)nodeA * 64 + quad * 8;
    const ushort_t* apB = h_bf + (size_t)nodeB * 64 + quad * 8;
    short8 aA0 = *(const short8*)apA;
    short8 aA1 = *(const short8*)(apA + 32);
    short8 aB0 = *(const short8*)apB;
    short8 aB1 = *(const short8*)(apB + 32);
    int ct_start = (wave < 2) ? wave * 4 : (8 + (wave - 2) * 3);
    int ct_cnt = (wave < 2) ? 4 : 3;
    for (int i = 0; i < ct_cnt; ++i) {
        int ct = ct_start + i;
        const ushort_t* bp = Wall_arr + (size_t)ct * 1024 + lane * 8;
        short8 b0 = *(const short8*)bp;
        short8 b1 = *(const short8*)(bp + 512);
        float4v cA = {0.f, 0.f, 0.f, 0.f};
        float4v cB = {0.f, 0.f, 0.f, 0.f};
        cA = __builtin_amdgcn_mfma_f32_16x16x32_bf16(aA0, b0, cA, 0, 0, 0);
        cA = __builtin_amdgcn_mfma_f32_16x16x32_bf16(aA1, b1, cA, 0, 0, 0);
        cB = __builtin_amdgcn_mfma_f32_16x16x32_bf16(aB0, b0, cB, 0, 0, 0);
        cB = __builtin_amdgcn_mfma_f32_16x16x32_bf16(aB1, b1, cB, 0, 0, 0);
        int col = ct * 16 + nn;
        float bias = Wall_bias[col];
        gemm_store(col, bias, cA, n0 + quad * 4, N, qk2buf, outbuf, qcbuf);
        gemm_store(col, bias, cB, n0 + 16 + quad * 4, N, qk2buf, outbuf, qcbuf);
    }
}

// ---------------- fused BN-apply(l) + GEMM(l+1): 32 nodes/block ----------------

__global__ __launch_bounds__(256) void bnqkv_kernel(
    const float* __restrict__ outbuf_in, const float* __restrict__ bnsums,
    const float* __restrict__ gamma, const float* __restrict__ beta,
    float* __restrict__ h, ushort_t* __restrict__ h_bf,
    const ushort_t* __restrict__ Wall_arr, const float* __restrict__ Wall_bias,
    ushort_t* __restrict__ qk2buf, float* __restrict__ outbuf, float* __restrict__ qcbuf,
    int N) {
    __shared__ ushort_t hb[32 * 64];
    __shared__ float ss_scale[64], ss_shift[64];
    int t = threadIdx.x;
    if (t < 64) {
        float invN = 1.f / (float)N;
        float mean = bnsums[t] * invN;
        float var = bnsums[64 + t] * invN - mean * mean;
        float sc = gamma[t] * rsqrtf(var + 1e-5f);
        ss_scale[t] = sc;
        ss_shift[t] = beta[t] - mean * sc;
    }
    __syncthreads();
    int n0 = blockIdx.x * 32;
    int c = t & 63;
    float sc = ss_scale[c], sh = ss_shift[c];
#pragma unroll
    for (int i = 0; i < 8; ++i) {
        int li = t + i * 256;
        int gidx = n0 * 64 + li;
        float hn = 0.f;
        if (gidx < N * 64) {
            float o = outbuf_in[gidx] * sc + sh;
            o = (o > 0.f) ? o : 0.01f * o;
            hn = h[gidx] + o;
            h[gidx] = hn;
            h_bf[gidx] = f2bf(hn);   // gather target for next attn layer
        }
        hb[li] = f2bf(hn);
    }
    __syncthreads();
    int wave = t >> 6, lane = t & 63;
    int quad = lane >> 4, nn = lane & 15;
    const ushort_t* apA = hb + nn * 64 + quad * 8;
    const ushort_t* apB = hb + (16 + nn) * 64 + quad * 8;
    short8 aA0 = *(const short8*)apA;
    short8 aA1 = *(const short8*)(apA + 32);
    short8 aB0 = *(const short8*)apB;
    short8 aB1 = *(const short8*)(apB + 32);
    int ct_start = (wave < 2) ? wave * 4 : (8 + (wave - 2) * 3);
    int ct_cnt = (wave < 2) ? 4 : 3;
    for (int i = 0; i < ct_cnt; ++i) {
        int ct = ct_start + i;
        const ushort_t* bp = Wall_arr + (size_t)ct * 1024 + lane * 8;
        short8 b0 = *(const short8*)bp;
        short8 b1 = *(const short8*)(bp + 512);
        float4v cA = {0.f, 0.f, 0.f, 0.f};
        float4v cB = {0.f, 0.f, 0.f, 0.f};
        cA = __builtin_amdgcn_mfma_f32_16x16x32_bf16(aA0, b0, cA, 0, 0, 0);
        cA = __builtin_amdgcn_mfma_f32_16x16x32_bf16(aA1, b1, cA, 0, 0, 0);
        cB = __builtin_amdgcn_mfma_f32_16x16x32_bf16(aB0, b0, cB, 0, 0, 0);
        cB = __builtin_amdgcn_mfma_f32_16x16x32_bf16(aB1, b1, cB, 0, 0, 0);
        int col = ct * 16 + nn;
        float bias = Wall_bias[col];
        gemm_store(col, bias, cA, n0 + quad * 4, N, qk2buf, outbuf, qcbuf);
        gemm_store(col, bias, cB, n0 + 16 + quad * 4, N, qk2buf, outbuf, qcbuf);
    }
}

// ---------------- attention: gather h_src only (128B/edge) ----------------
// 16-lane node groups, 4 nodes/wave, 16 nodes/block.
// lane l16: head = l16>>3, l8 = l16&7 holds h_src channels 8*l8..8*l8+7.
// logits = qk2[dst]·h_src + qc·ea + qb   (all 0.125-scaled at compose time)
// accumulates hacc = sum p*h_src (per head) and se = sum p*ea; V applied later.

__global__ __launch_bounds__(256) void attn_kernel(
    const ushort_t* __restrict__ h_bf, const ushort_t* __restrict__ qk2buf,
    const float* __restrict__ qcbuf,
    const char* __restrict__ erec, const int* __restrict__ rowptr,
    ushort_t* __restrict__ haccn, float* __restrict__ sen, float* __restrict__ degw,
    int N) {
    int t = threadIdx.x;
    int lane = t & 63, wid = t >> 6;
    int grp = lane >> 4, l16 = lane & 15;
    int head = l16 >> 3, l8 = l16 & 7;
    const char* hbb = (const char*)h_bf;

    int n = blockIdx.x * 16 + wid * 4 + grp;
    bool active = (n < N);
    int nn = active ? n : (N - 1);
    int start = rowptr[nn];
    int deg = active ? (rowptr[nn + 1] - start) : 0;
    int wdeg = deg;
    wdeg = max(wdeg, __shfl_xor(wdeg, 16));
    wdeg = max(wdeg, __shfl_xor(wdeg, 32));

    float lsum = 0.f;
    float hacc[8] = {0.f, 0.f, 0.f, 0.f, 0.f, 0.f, 0.f, 0.f};
    float se[8]   = {0.f, 0.f, 0.f, 0.f, 0.f, 0.f, 0.f, 0.f};

    if (wdeg > 0) {
        // qk2 fragment: 8 channels of the dst node's composed query (this head)
        uint4 qr = *(const uint4*)((const char*)qk2buf + (size_t)nn * 256 + head * 128 + l8 * 16);
        float qk0 = bfu_lo(qr.x), qk1 = bfu_hi(qr.x);
        float qk2f = bfu_lo(qr.y), qk3 = bfu_hi(qr.y);
        float qk4 = bfu_lo(qr.z), qk5 = bfu_hi(qr.z);
        float qk6 = bfu_lo(qr.w), qk7 = bfu_hi(qr.w);
        const float* qcp = qcbuf + (size_t)nn * 20;
        float4 qcA = *(const float4*)(qcp + head * 8);
        float4 qcB = *(const float4*)(qcp + head * 8 + 4);
        float qb = qcp[16 + head];

        bool dpos = (deg > 0);
        int dclamp = dpos ? (deg - 1) : 0;

        // 16-edge src-offset window held across the group's lanes (stride-32B reads)
        int offL = *(const int*)(erec + (size_t)(dpos ? (start + min(l16, dclamp)) : 0) * 32);
        int o0 = __shfl(offL, grp * 16);
        uint4 ca = *(const uint4*)(hbb + (size_t)(unsigned)o0 + l8 * 16);
        int gi0 = dpos ? start : 0;
        uint4 ev = *(const uint4*)(erec + (size_t)gi0 * 32 + 16);

        for (int it = 0; it < wdeg; ++it) {
            int itn = it + 1;
            if ((itn & 15) == 0)
                offL = *(const int*)(erec +
                        (size_t)(dpos ? (start + min(itn + l16, dclamp)) : 0) * 32);
            int itc = min(itn, wdeg - 1);
            int on = __shfl(offL, grp * 16 + (itc & 15));
            uint4 na = *(const uint4*)(hbb + (size_t)(unsigned)on + l8 * 16);
            int gin = dpos ? (start + min(itc, dclamp)) : 0;
            uint4 fv = *(const uint4*)(erec + (size_t)gin * 32 + 16);

            float h0 = bfu_lo(ca.x), h1 = bfu_hi(ca.x);
            float h2 = bfu_lo(ca.y), h3 = bfu_hi(ca.y);
            float h4 = bfu_lo(ca.z), h5 = bfu_hi(ca.z);
            float h6 = bfu_lo(ca.w), h7 = bfu_hi(ca.w);
            float dt = qk0 * h0 + qk1 * h1 + qk2f * h2 + qk3 * h3
                     + qk4 * h4 + qk5 * h5 + qk6 * h6 + qk7 * h7;
            dt += __shfl_xor(dt, 1);
            dt += __shfl_xor(dt, 2);
            dt += __shfl_xor(dt, 4);
            float ex0 = bfu_lo(ev.x), ex1 = bfu_hi(ev.x);
            float ex2 = bfu_lo(ev.y), ex3 = bfu_hi(ev.y);
            float ex4 = bfu_lo(ev.z), ex5 = bfu_hi(ev.z);
            float ex6 = bfu_lo(ev.w), ex7 = bfu_hi(ev.w);
            float s0 = dt
                     + qcA.x * ex0 + qcA.y * ex1 + qcA.z * ex2 + qcA.w * ex3
                     + qcB.x * ex4 + qcB.y * ex5 + qcB.z * ex6 + qcB.w * ex7
                     + qb;
            float p = (it < deg) ? __expf(fmaxf(s0, -60.f)) : 0.f;
            lsum += p;
            hacc[0] += p * h0; hacc[1] += p * h1;
            hacc[2] += p * h2; hacc[3] += p * h3;
            hacc[4] += p * h4; hacc[5] += p * h5;
            hacc[6] += p * h6; hacc[7] += p * h7;
            se[0] += p * ex0; se[1] += p * ex1; se[2] += p * ex2; se[3] += p * ex3;
            se[4] += p * ex4; se[5] += p * ex5; se[6] += p * ex6; se[7] += p * ex7;
            ca = na; ev = fv;
        }
    }

    if (active) {
        float inv = (deg > 0) ? (0.5f / lsum) : 0.f;   // 0.5 = head mean
        unsigned pw0 = (unsigned)f2bf(hacc[0] * inv) | ((unsigned)f2bf(hacc[1] * inv) << 16);
        unsigned pw1 = (unsigned)f2bf(hacc[2] * inv) | ((unsigned)f2bf(hacc[3] * inv) << 16);
        unsigned pw2 = (unsigned)f2bf(hacc[4] * inv) | ((unsigned)f2bf(hacc[5] * inv) << 16);
        unsigned pw3 = (unsigned)f2bf(hacc[6] * inv) | ((unsigned)f2bf(hacc[7] * inv) << 16);
        uint4 pk = make_uint4(pw0, pw1, pw2, pw3);
        *(uint4*)((char*)haccn + (size_t)nn * 256 + head * 128 + l8 * 16) = pk;
        if (l8 == 0) {
            *(float4*)(sen + (size_t)nn * 16 + head * 8) =
                make_float4(se[0] * inv, se[1] * inv, se[2] * inv, se[3] * inv);
            *(float4*)(sen + (size_t)nn * 16 + head * 8 + 4) =
                make_float4(se[4] * inv, se[5] * inv, se[6] * inv, se[7] * inv);
            if (head == 0) degw[nn] = (deg > 0) ? 1.f : 0.f;
        }
    }
}

// ---------------- vapply: out = haccn @ Wv_stk + ep-compose + cst + skip; BN partials --

__global__ __launch_bounds__(256) void vapply_kernel(
    const ushort_t* __restrict__ haccn, const float* __restrict__ sen,
    const float* __restrict__ degw,
    const ushort_t* __restrict__ wv_arr, const float* __restrict__ Wc,
    const float* __restrict__ cst,
    float* __restrict__ outbuf, float* __restrict__ part, int N) {
    __shared__ float Wc_s[1024];
    __shared__ float cst_s[64];
    __shared__ float sen_s[32][16];
    __shared__ float dw_s[32];
    __shared__ float ps[128];
    int t = threadIdx.x;
    for (int i = t; i < 1024; i += 256) Wc_s[i] = Wc[i];
    if (t < 64) cst_s[t] = cst[t];
    int n0 = blockIdx.x * 32;
    for (int i = t; i < 512; i += 256) {
        int ln2 = i >> 4;
        int nc = n0 + ln2; if (nc >= N) nc = N - 1;
        sen_s[ln2][i & 15] = sen[(size_t)nc * 16 + (i & 15)];
    }
    if (t < 32) {
        int nc = n0 + t; if (nc >= N) nc = N - 1;
        dw_s[t] = degw[nc];
    }
    __syncthreads();
    int wave = t >> 6, lane = t & 63;
    int quad = lane >> 4, nn = lane & 15;
    int nodeA = n0 + nn;       if (nodeA >= N) nodeA = N - 1;
    int nodeB = n0 + 16 + nn;  if (nodeB >= N) nodeB = N - 1;
    int ct = wave;
    float4v cA = {0.f, 0.f, 0.f, 0.f};
    float4v cB = {0.f, 0.f, 0.f, 0.f};
#pragma unroll
    for (int kc = 0; kc < 4; ++kc) {
        short8 aA = *(const short8*)(haccn + (size_t)nodeA * 128 + kc * 32 + quad * 8);
        short8 aB = *(const short8*)(haccn + (size_t)nodeB * 128 + kc * 32 + quad * 8);
        short8 bb = *(const short8*)(wv_arr + kc * 2048 + ct * 512 + lane * 8);
        cA = __builtin_amdgcn_mfma_f32_16x16x32_bf16(aA, bb, cA, 0, 0, 0);
        cB = __builtin_amdgcn_mfma_f32_16x16x32_bf16(aB, bb, cB, 0, 0, 0);
    }
    int col = ct * 16 + nn;
    float sa = 0.f, sq = 0.f;
#pragma unroll
    for (int g = 0; g < 2; ++g) {
        float4v acc = g ? cB : cA;
        int lbase = g * 16 + quad * 4;
#pragma unroll
        for (int r = 0; r < 4; ++r) {
            int ln2 = lbase + r;
            int nr = n0 + ln2;
            const float* sp = sen_s[ln2];
            float ep = 0.f;
#pragma unroll
            for (int hh = 0; hh < 2; ++hh)
#pragma unroll
                for (int d = 0; d < 8; ++d)
                    ep += sp[hh * 8 + d] * Wc_s[d * 128 + hh * 64 + col];
            if (nr < N) {
                float val = acc[r] + ep + dw_s[ln2] * cst_s[col] +
                            outbuf[(size_t)nr * 64 + col];
                outbuf[(size_t)nr * 64 + col] = val;
                sa += val;
                sq += val * val;
            }
        }
    }
    sa += __shfl_xor(sa, 16); sa += __shfl_xor(sa, 32);
    sq += __shfl_xor(sq, 16); sq += __shfl_xor(sq, 32);
    if (quad == 0) { ps[col] = sa; ps[64 + col] = sq; }
    __syncthreads();
    if (t < 128) part[(size_t)blockIdx.x * 128 + t] = ps[t];
}

// ---------------- BN reduce + final-layer apply w/ gate ----------------

__global__ __launch_bounds__(256) void bnreduce_kernel(const float* __restrict__ part,
                                                       float* __restrict__ bnsums, int nb) {
    int s = blockIdx.x;  // 0..127
    int t = threadIdx.x;
    float a = 0.f;
    for (int b = t; b < nb; b += 256) a += part[(size_t)b * 128 + s];
    __shared__ float sh[256];
    sh[t] = a;
    __syncthreads();
    for (int d = 128; d; d >>= 1) {
        if (t < d) sh[t] += sh[t + d];
        __syncthreads();
    }
    if (t == 0) bnsums[s] = sh[0];
}

__global__ __launch_bounds__(256) void bnapply_kernel(
    const float* __restrict__ outbuf, const float* __restrict__ bnsums,
    const float* __restrict__ gamma, const float* __restrict__ beta,
    const float* __restrict__ gate_W, const float* __restrict__ gate_b,
    float* __restrict__ h, float* __restrict__ gatebuf, int N) {
    int idx = blockIdx.x * 256 + threadIdx.x;
    if (idx >= N * 64) return;
    int c = idx & 63, n = idx >> 6;
    float invN = 1.f / (float)N;
    float mean = bnsums[c] * invN;
    float var = bnsums[64 + c] * invN - mean * mean;
    float scale = gamma[c] * rsqrtf(var + 1e-5f);
    float shift = beta[c] - mean * scale;
    float o = outbuf[idx] * scale + shift;
    o = (o > 0.f) ? o : 0.01f * o;
    float hn = h[idx] + o;
    h[idx] = hn;
    float g = hn * gate_W[c];
#pragma unroll
    for (int off = 32; off; off >>= 1) g += __shfl_xor(g, off);
    if (c == 0) gatebuf[n] = g + gate_b[0];
}

// ---------------- pooling (max fused into acc) ----------------

__global__ __launch_bounds__(256) void pool_acc_kernel(
    const float* __restrict__ h, const float* __restrict__ gatebuf,
    const int* __restrict__ batch,
    float* __restrict__ pacc, float* __restrict__ pden, int N) {
    int b = blockIdx.x >> 3, chunk = blockIdx.x & 7;
    int lo = 0, hi = N;
    while (lo < hi) { int mid = (lo + hi) >> 1; if (batch[mid] < b) lo = mid + 1; else hi = mid; }
    int start = lo;
    lo = start; hi = N;
    while (lo < hi) { int mid = (lo + hi) >> 1; if (batch[mid] <= b) lo = mid + 1; else hi = mid; }
    int end = lo;
    int t = threadIdx.x, lane = t & 63, wid = t >> 6;
    __shared__ float sm[4];
    float mx = -1e30f;
    for (int n = start + t; n < end; n += 256) mx = fmaxf(mx, gatebuf[n]);
#pragma unroll
    for (int off = 32; off; off >>= 1) mx = fmaxf(mx, __shfl_xor(mx, off));
    if (lane == 0) sm[wid] = mx;
    __syncthreads();
    float mb = fmaxf(fmaxf(sm[0], sm[1]), fmaxf(sm[2], sm[3]));
    int gwid = chunk * 4 + wid;
    float acc = 0.f, den = 0.f;
    for (int n = start + gwid; n < end; n += 32) {
        float ge = __expf(gatebuf[n] - mb);
        acc += ge * h[(size_t)n * 64 + lane];
        den += ge;
    }
    __shared__ float sacc[4][64];
    __shared__ float sden[4];
    sacc[wid][lane] = acc;
    if (lane == 0) sden[wid] = den;
    __syncthreads();
    if (wid == 0) {
        pacc[(size_t)blockIdx.x * 64 + lane] =
            sacc[0][lane] + sacc[1][lane] + sacc[2][lane] + sacc[3][lane];
        if (lane == 0) pden[blockIdx.x] = sden[0] + sden[1] + sden[2] + sden[3];
    }
}

__global__ void pool_fin_kernel(const float* __restrict__ pacc, const float* __restrict__ pden,
                                const float* __restrict__ out_W, const float* __restrict__ out_b,
                                float* __restrict__ out) {
    int b = blockIdx.x, c = threadIdx.x;
    float pc = 0.f, dv = 0.f;
#pragma unroll
    for (int j = 0; j < 8; ++j) {
        pc += pacc[(size_t)(b * 8 + j) * 64 + c];
        dv += pden[b * 8 + j];
    }
    float s = pc * out_W[c];
#pragma unroll
    for (int off = 32; off; off >>= 1) s += __shfl_xor(s, off);
    if (c == 0) {
        if (dv <= 0.f) dv = 1.f;
        float v = s / dv + out_b[0];
        out[b] = 1.f / (1.f + __expf(-v));
    }
}

// ---------------- host ----------------

extern "C" void kernel_launch(void* const* d_in, const int* in_sizes, int n_in,
                              void* d_out, int out_size, void* d_ws, size_t ws_size,
                              hipStream_t stream) {
    const float* x         = (const float*)d_in[0];
    const float* edge_attr = (const float*)d_in[1];
    const int*   edge_src  = (const int*)d_in[2];
    const int*   edge_dst  = (const int*)d_in[3];
    const int*   batch     = (const int*)d_in[4];
    const float* node_W    = (const float*)d_in[5];
    const float* node_b    = (const float*)d_in[6];
    const float* edge_W    = (const float*)d_in[7];
    const float* edge_b    = (const float*)d_in[8];
    const float* Wq        = (const float*)d_in[9];
    const float* bq        = (const float*)d_in[10];
    const float* Wk        = (const float*)d_in[11];
    const float* bk        = (const float*)d_in[12];
    const float* Wv        = (const float*)d_in[13];
    const float* bv        = (const float*)d_in[14];
    const float* We        = (const float*)d_in[15];
    const float* be        = (const float*)d_in[16];
    const float* Wskip     = (const float*)d_in[17];
    const float* bskip     = (const float*)d_in[18];
    const float* gamma     = (const float*)d_in[19];
    const float* beta      = (const float*)d_in[20];
    const float* gate_W    = (const float*)d_in[21];
    const float* gate_b    = (const float*)d_in[22];
    const float* out_W     = (const float*)d_in[23];
    const float* out_b     = (const float*)d_in[24];
    float* out = (float*)d_out;

    const int N = in_sizes[0] / 16;
    const int E = in_sizes[2];
    const int nba = (N + 15) / 16;   // attn blocks: 16 nodes per block
    const int nbv = (N + 31) / 32;   // vapply / gemm blocks: 32 nodes per block

    char* ws = (char*)d_ws;
    size_t off = 0;
    auto alloc = [&](size_t bytes) {
        size_t o = off;
        off += (bytes + 255) & ~(size_t)255;
        return o;
    };
    float*    h        = (float*)(ws + alloc((size_t)N * 64 * 4));
    ushort_t* h_bf     = (ushort_t*)(ws + alloc((size_t)N * 64 * 2));
    ushort_t* qk2buf   = (ushort_t*)(ws + alloc((size_t)N * 128 * 2));
    float*    outbuf   = (float*)(ws + alloc((size_t)N * 64 * 4));
    float*    qcbuf    = (float*)(ws + alloc((size_t)N * 20 * 4));
    ushort_t* haccn    = (ushort_t*)(ws + alloc((size_t)N * 128 * 2));
    float*    sen      = (float*)(ws + alloc((size_t)N * 16 * 4));
    float*    degw     = (float*)(ws + alloc((size_t)N * 4));
    int*      rowptr   = (int*)(ws + alloc((size_t)(N + 1) * 4));
    int*      cursor   = (int*)(ws + alloc((size_t)N * 4));
    int*      counts   = (int*)(ws + alloc((size_t)N * 4));
    int*      bsums    = (int*)(ws + alloc(1024));
    char*     erec     = (char*)(ws + alloc((size_t)E * 32));
    float*    Wc       = (float*)(ws + alloc(2 * 1024 * 4));
    float*    bcb      = (float*)(ws + alloc(2 * 128 * 4));
    ushort_t* Wall_arr = (ushort_t*)(ws + alloc(2 * 14336 * 2));
    float*    Wall_b   = (float*)(ws + alloc(2 * 224 * 4));
    ushort_t* wv_arr   = (ushort_t*)(ws + alloc(2 * 8192 * 2));
    float*    cst      = (float*)(ws + alloc(2 * 64 * 4));
    float*    bnsums   = (float*)(ws + alloc(128 * 4));
    float*    gatebuf  = (float*)(ws + alloc((size_t)N * 4));
    float*    part     = (float*)(ws + alloc((size_t)nbv * 128 * 4));
    float*    pacc     = (float*)(ws + alloc((size_t)512 * 64 * 4));
    float*    pden     = (float*)(ws + alloc(512 * 4));
    if (off > ws_size) return;

    int O0 = (N * 64 + 255) / 256;
    int O1 = O0 + (N + 255) / 256;
    int O2 = O1 + 9;
    int O3 = O2 + 178;   // 2*14336 + 2*224 + 2*8192 = 45504 -> 178 blocks
    setup_kernel<<<O3, 256, 0, stream>>>(
        x, node_W, node_b, edge_W, edge_b, We, be, Wq, bq, Wk, bk, Wv, bv, Wskip, bskip,
        h, h_bf, counts, Wc, bcb, Wall_arr, Wall_b, wv_arr, O0, O1, O2, N);
    combine2_kernel<<<10, 256, 0, stream>>>(Wq, bq, bk, bv, Wc, bcb, Wall_arr, Wall_b, cst);

    csr_count_kernel<<<(E + 255) / 256, 256, 0, stream>>>(edge_dst, counts, E);
    int nb = (N + 255) / 256;
    scan1_kernel<<<nb, 256, 0, stream>>>(counts, rowptr, bsums, N);
    scan3_kernel<<<nb, 256, 0, stream>>>(rowptr, bsums, cursor, N, E, nb);
    csr_fill_kernel<<<(E + 255) / 256, 256, 0, stream>>>(edge_dst, edge_src, edge_attr,
                                                         cursor, erec, E);

    // layer 0
    qkv_mfma_kernel<<<nbv, 256, 0, stream>>>(
        h_bf, Wall_arr, Wall_b, qk2buf, outbuf, qcbuf, N);
    attn_kernel<<<nba, 256, 0, stream>>>(h_bf, qk2buf, qcbuf, erec,
                                         rowptr, haccn, sen, degw, N);
    vapply_kernel<<<nbv, 256, 0, stream>>>(haccn, sen, degw, wv_arr, Wc, cst,
                                           outbuf, part, N);
    bnreduce_kernel<<<128, 256, 0, stream>>>(part, bnsums, nbv);
    bnqkv_kernel<<<nbv, 256, 0, stream>>>(
        outbuf, bnsums, gamma, beta, h, h_bf,
        Wall_arr + 14336, Wall_b + 224, qk2buf, outbuf, qcbuf, N);

    // layer 1
    attn_kernel<<<nba, 256, 0, stream>>>(h_bf, qk2buf, qcbuf, erec,
                                         rowptr, haccn, sen, degw, N);
    vapply_kernel<<<nbv, 256, 0, stream>>>(haccn, sen, degw, wv_arr + 8192, Wc + 1024,
                                           cst + 64, outbuf, part, N);
    bnreduce_kernel<<<128, 256, 0, stream>>>(part, bnsums, nbv);
    bnapply_kernel<<<(N * 64 + 255) / 256, 256, 0, stream>>>(
        outbuf, bnsums, gamma + 64, beta + 64, gate_W, gate_b, h, gatebuf, N);

    pool_acc_kernel<<<512, 256, 0, stream>>>(h, gatebuf, batch, pacc, pden, N);
    pool_fin_kernel<<<64, 64, 0, stream>>>(pacc, pden, out_W, out_b, out);
}

// Round 6
// 341.450 us; speedup vs baseline: 2.1094x; 1.0232x over previous
//
#include <hip/hip_runtime.h>
#include <hip/hip_bf16.h>

typedef unsigned short ushort_t;
typedef __attribute__((ext_vector_type(8))) short short8;
typedef __attribute__((ext_vector_type(4))) float float4v;

__device__ __forceinline__ float bfu_lo(unsigned u) {
    return __uint_as_float(u << 16);
}
__device__ __forceinline__ float bfu_hi(unsigned u) {
    return __uint_as_float(u & 0xffff0000u);
}
__device__ __forceinline__ ushort_t f2bf(float f) {
    __hip_bfloat16 h = __float2bfloat16(f);
    return *reinterpret_cast<ushort_t*>(&h);
}

// Wall layout per layer: 14 col-tiles (210 cols used), tile = 1024 ushorts:
//   idx = ct*1024 + kch*512 + lane*8 + j   (k = kch*32 + quad*8 + j, col = ct*16 + nn)
// cols: 0..127 qk2 (composed 0.125*Wq·Wk^T) | 128..191 skip | 192..209 qc (composed ea)
// Edge record (32 B, sector-aligned): +0 src byte-offset (int), +16 ea bf16x8.

// ---------------- fused setup ----------------

__global__ __launch_bounds__(256) void setup_kernel(
    const float* __restrict__ x, const float* __restrict__ node_W,
    const float* __restrict__ node_b,
    const float* __restrict__ edge_W, const float* __restrict__ edge_b,
    const float* __restrict__ We, const float* __restrict__ be,
    const float* __restrict__ Wq, const float* __restrict__ bq,
    const float* __restrict__ Wk, const float* __restrict__ bk,
    const float* __restrict__ Wv, const float* __restrict__ bv,
    const float* __restrict__ Wskip, const float* __restrict__ bskip,
    float* __restrict__ h, ushort_t* __restrict__ h_bf,
    int* __restrict__ counts,
    float* __restrict__ Wc, float* __restrict__ bcb,
    ushort_t* __restrict__ Wall_arr, float* __restrict__ Wall_bias,
    ushort_t* __restrict__ wv_arr,
    int O0, int O1, int O2, int N) {
    int b = blockIdx.x, t = threadIdx.x;
    if (b < O0) {
        int idx = b * 256 + t;
        if (idx < N * 64) {
            int n = idx >> 6, c = idx & 63;
            float acc = node_b[c];
#pragma unroll
            for (int j = 0; j < 16; ++j) acc += x[n * 16 + j] * node_W[j * 64 + c];
            h[idx] = acc;
            h_bf[idx] = f2bf(acc);
        }
    } else if (b < O1) {
        int i = (b - O0) * 256 + t;
        if (i < N) counts[i] = 0;
    } else if (b < O2) {
        int tid = (b - O1) * 256 + t;
        if (tid < 2048) {
            int l = tid >> 10, d = (tid >> 7) & 7, j = tid & 127;
            float s = 0.f;
            for (int m = 0; m < 64; ++m) s += edge_W[d * 64 + m] * We[l * 8192 + m * 128 + j];
            Wc[l * 1024 + d * 128 + j] = s;
        } else if (tid < 2048 + 256) {
            int u = tid - 2048;
            int l = u >> 7, j = u & 127;
            float s = be[l * 128 + j];
            for (int m = 0; m < 64; ++m) s += edge_b[m] * We[l * 8192 + m * 128 + j];
            bcb[l * 128 + j] = s;
        }
    } else {
        int tid = (b - O2) * 256 + t;
        if (tid < 2 * 14336) {
            int l = tid / 14336, u = tid % 14336;
            int j = u & 7, ln = (u >> 3) & 63, kch = (u >> 9) & 1, ct = u >> 10;
            int nn = ln & 15, quad = ln >> 4;
            int k = kch * 32 + quad * 8 + j;
            int col = ct * 16 + nn;
            float v = 0.f;
            if (col < 128) {
                // composed 0.125 * (Wq_h Wk_h^T)[k, m]
                int hh = col >> 6, m = col & 63;
                const float* wq = Wq + l * 8192 + k * 128 + hh * 64;
                const float* wk = Wk + l * 8192 + m * 128 + hh * 64;
                float s = 0.f;
                for (int c2 = 0; c2 < 64; ++c2) s += wq[c2] * wk[c2];
                v = 0.125f * s;
            } else if (col < 192) {
                v = Wskip[l * 4096 + k * 64 + (col - 128)];
            }  // cols 192..223: 0 here; combine2 fills 192..209
            Wall_arr[(size_t)l * 14336 + ct * 1024 + kch * 512 + ln * 8 + j] = f2bf(v);
        } else if (tid < 2 * 14336 + 2 * 224) {
            int u = tid - 2 * 14336;
            int l = u / 224, col = u % 224;
            float v = 0.f;
            if (col < 128) {
                int hh = col >> 6, m = col & 63;
                const float* bqp = bq + l * 128 + hh * 64;
                const float* wk = Wk + l * 8192 + m * 128 + hh * 64;
                float s = 0.f;
                for (int c2 = 0; c2 < 64; ++c2) s += bqp[c2] * wk[c2];
                v = 0.125f * s;
            } else if (col < 192) {
                v = bskip[l * 64 + col - 128];
            }
            Wall_bias[l * 224 + col] = v;
        } else if (tid < 2 * 14336 + 2 * 224 + 2 * 8192) {
            // Wv stacked tiles: B[p = h*64+m][c] = Wv[m, h*64+c]
            // flat r = kc*2048 + ct*512 + ln*8 + j
            int u = tid - (2 * 14336 + 2 * 224);
            int l = u >> 13, r = u & 8191;
            int j = r & 7, ln = (r >> 3) & 63, ct = (r >> 9) & 3, kc = r >> 11;
            int quad = ln >> 4, nn = ln & 15;
            int p = kc * 32 + quad * 8 + j;
            int hh = p >> 6, m = p & 63;
            int c2 = ct * 16 + nn;
            wv_arr[(size_t)l * 8192 + r] = f2bf(Wv[l * 8192 + m * 128 + hh * 64 + c2]);
        }
    }
}

// combine2: qc composed columns (ea-dot path, with q·bk folded into bias cols) + cst
__global__ void combine2_kernel(const float* __restrict__ Wq, const float* __restrict__ bq,
                                const float* __restrict__ bk, const float* __restrict__ bv,
                                const float* __restrict__ Wc, const float* __restrict__ bcb,
                                ushort_t* __restrict__ Wall_arr, float* __restrict__ Wall_bias,
                                float* __restrict__ cst) {
    int tid = blockIdx.x * 256 + threadIdx.x;
    if (tid < 2304) {
        int l = tid / 1152, u = tid % 1152, k = u / 18, j = u % 18;
        float s = 0.f;
        if (j < 16) {
            int hh = j >> 3, d = j & 7;
            for (int c = 0; c < 64; ++c)
                s += Wq[l * 8192 + k * 128 + hh * 64 + c] * Wc[l * 1024 + d * 128 + hh * 64 + c];
        } else {
            int hh = j - 16;
            for (int c = 0; c < 64; ++c)
                s += Wq[l * 8192 + k * 128 + hh * 64 + c] *
                     (bcb[l * 128 + hh * 64 + c] + bk[l * 128 + hh * 64 + c]);
        }
        s *= 0.125f;
        int col = 192 + j;
        int ct = col >> 4, nn = col & 15;
        int kch = k >> 5, quad = (k >> 3) & 3, jj = k & 7;
        int ln = quad * 16 + nn;
        Wall_arr[(size_t)l * 14336 + ct * 1024 + kch * 512 + ln * 8 + jj] = f2bf(s);
    } else if (tid < 2304 + 36) {
        int u = tid - 2304;
        int l = u / 18, j = u % 18;
        float s = 0.f;
        if (j < 16) {
            int hh = j >> 3, d = j & 7;
            for (int c = 0; c < 64; ++c)
                s += bq[l * 128 + hh * 64 + c] * Wc[l * 1024 + d * 128 + hh * 64 + c];
        } else {
            int hh = j - 16;
            for (int c = 0; c < 64; ++c)
                s += bq[l * 128 + hh * 64 + c] *
                     (bcb[l * 128 + hh * 64 + c] + bk[l * 128 + hh * 64 + c]);
        }
        Wall_bias[l * 224 + 192 + j] = 0.125f * s;
    } else if (tid < 2304 + 36 + 128) {
        int u = tid - 2340;
        int l = u >> 6, c = u & 63;
        cst[l * 64 + c] = 0.5f * (bv[l * 128 + c] + bv[l * 128 + 64 + c] +
                                  bcb[l * 128 + c] + bcb[l * 128 + 64 + c]);
    }
}

// ---------------- CSR build ----------------

__global__ void csr_count_kernel(const int* __restrict__ dst, int* __restrict__ counts, int E) {
    int e = blockIdx.x * 256 + threadIdx.x;
    if (e < E) atomicAdd(&counts[dst[e]], 1);
}

__global__ void scan1_kernel(const int* __restrict__ counts, int* __restrict__ rowptr,
                             int* __restrict__ bsums, int N) {
    __shared__ int s[256];
    int t = threadIdx.x, i = blockIdx.x * 256 + t;
    int v = (i < N) ? counts[i] : 0;
    s[t] = v;
    __syncthreads();
    for (int d = 1; d < 256; d <<= 1) {
        int x = (t >= d) ? s[t - d] : 0;
        __syncthreads();
        s[t] += x;
        __syncthreads();
    }
    if (i < N) rowptr[i] = s[t] - v;
    if (t == 255) bsums[blockIdx.x] = s[255];
}

__global__ void scan3_kernel(int* __restrict__ rowptr, const int* __restrict__ bsums,
                             int* __restrict__ cursor, int N, int E, int nb) {
    __shared__ int sh[256];
    int t = threadIdx.x;
    int v = (t < nb) ? bsums[t] : 0;
    sh[t] = v;
    __syncthreads();
    for (int d = 1; d < 256; d <<= 1) {
        int x = (t >= d) ? sh[t - d] : 0;
        __syncthreads();
        sh[t] += x;
        __syncthreads();
    }
    int blk = blockIdx.x;
    int offv = (blk == 0) ? 0 : sh[blk - 1];
    int i = blk * 256 + t;
    if (i < N) {
        int r = rowptr[i] + offv;
        rowptr[i] = r;
        cursor[i] = r;
    }
    if (i == 0) rowptr[N] = E;
}

// one 32-B record per edge: [src_off:int | pad:12B | ea bf16x8:16B]
__global__ void csr_fill_kernel(const int* __restrict__ dst, const int* __restrict__ src,
                                const float* __restrict__ edge_attr, int* __restrict__ cursor,
                                char* __restrict__ erec, int E) {
    int e = blockIdx.x * 256 + threadIdx.x;
    if (e < E) {
        int pos = atomicAdd(&cursor[dst[e]], 1);
        float4 a0 = *(const float4*)(edge_attr + (size_t)e * 8);
        float4 a1 = *(const float4*)(edge_attr + (size_t)e * 8 + 4);
        uint4 w1;
        w1.x = (unsigned)f2bf(a0.x) | ((unsigned)f2bf(a0.y) << 16);
        w1.y = (unsigned)f2bf(a0.z) | ((unsigned)f2bf(a0.w) << 16);
        w1.z = (unsigned)f2bf(a1.x) | ((unsigned)f2bf(a1.y) << 16);
        w1.w = (unsigned)f2bf(a1.z) | ((unsigned)f2bf(a1.w) << 16);
        char* rp = erec + (size_t)pos * 32;
        *(uint4*)rp = make_uint4((unsigned)(src[e] * 128), 0u, 0u, 0u);
        *(uint4*)(rp + 16) = w1;
    }
}

// ---------------- fused per-layer kernel: GEMM -> attn -> V-apply ----------------
// 512 threads = 8 waves, 32 nodes per block. All intermediates (qk2, qc, skip,
// hacc, se) live in LDS; only h_bf gather + erec stream + outbuf write hit HBM.

__global__ __launch_bounds__(512) void layer_kernel(
    const ushort_t* __restrict__ h_bf,
    const char* __restrict__ erec, const int* __restrict__ rowptr,
    const ushort_t* __restrict__ Wall_arr, const float* __restrict__ Wall_bias,
    const ushort_t* __restrict__ wv_arr, const float* __restrict__ Wc,
    const float* __restrict__ cst,
    float* __restrict__ outbuf, float* __restrict__ part, int N) {
    __shared__ ushort_t qk2_s[32][128];   // composed query, bf16
    __shared__ ushort_t ha_s[32][136];    // normalized hacc, bf16 (pad to 136)
    __shared__ float qc_s[32][20];        // 18 used: qcA(8) qcB(8) qb(2)
    __shared__ float skip_s[32][64];
    __shared__ float sen_s[32][16];
    __shared__ float dw_s[32];
    __shared__ float Wc_s[1024];
    __shared__ float cst_s[64];
    __shared__ float ps[2][128];
    int t = threadIdx.x;
    int lane = t & 63, wid = t >> 6;
    int n0 = blockIdx.x * 32;
    for (int i = t; i < 1024; i += 512) Wc_s[i] = Wc[i];
    if (t < 64) cst_s[t] = cst[t];

    // ---- Phase 0: GEMM [32x64]@[64x210] from global h_bf into LDS ----
    {
        int quad = lane >> 4, nn16 = lane & 15;
        int nodeA = n0 + nn16;      if (nodeA >= N) nodeA = N - 1;
        int nodeB = n0 + 16 + nn16; if (nodeB >= N) nodeB = N - 1;
        const ushort_t* apA = h_bf + (size_t)nodeA * 64 + quad * 8;
        const ushort_t* apB = h_bf + (size_t)nodeB * 64 + quad * 8;
        short8 aA0 = *(const short8*)apA;
        short8 aA1 = *(const short8*)(apA + 32);
        short8 aB0 = *(const short8*)apB;
        short8 aB1 = *(const short8*)(apB + 32);
        for (int ct = wid; ct < 14; ct += 8) {
            const ushort_t* bp = Wall_arr + (size_t)ct * 1024 + lane * 8;
            short8 b0 = *(const short8*)bp;
            short8 b1 = *(const short8*)(bp + 512);
            float4v cA = {0.f, 0.f, 0.f, 0.f};
            float4v cB = {0.f, 0.f, 0.f, 0.f};
            cA = __builtin_amdgcn_mfma_f32_16x16x32_bf16(aA0, b0, cA, 0, 0, 0);
            cA = __builtin_amdgcn_mfma_f32_16x16x32_bf16(aA1, b1, cA, 0, 0, 0);
            cB = __builtin_amdgcn_mfma_f32_16x16x32_bf16(aB0, b0, cB, 0, 0, 0);
            cB = __builtin_amdgcn_mfma_f32_16x16x32_bf16(aB1, b1, cB, 0, 0, 0);
            int col = ct * 16 + nn16;
            float bias = Wall_bias[col];
#pragma unroll
            for (int g = 0; g < 2; ++g) {
                float4v c = g ? cB : cA;
                int lbase = g * 16 + quad * 4;
#pragma unroll
                for (int r = 0; r < 4; ++r) {
                    float v = c[r] + bias;
                    int ln2 = lbase + r;
                    if (col < 128) qk2_s[ln2][col] = f2bf(v);
                    else if (col < 192) skip_s[ln2][col - 128] = v;
                    else if (col < 210) qc_s[ln2][col - 192] = v;
                }
            }
        }
    }
    __syncthreads();

    // ---- Phase 1: attention (gather h_bf 128B/edge, stream erec) ----
    {
        int grp = lane >> 4, l16 = lane & 15;
        int head = l16 >> 3, l8 = l16 & 7;
        const char* hbb = (const char*)h_bf;
        int ln = wid * 4 + grp;             // local node 0..31
        int n = n0 + ln;
        bool active = (n < N);
        int nn = active ? n : (N - 1);
        int start = rowptr[nn];
        int deg = active ? (rowptr[nn + 1] - start) : 0;
        int wdeg = deg;
        wdeg = max(wdeg, __shfl_xor(wdeg, 16));
        wdeg = max(wdeg, __shfl_xor(wdeg, 32));

        float lsum = 0.f;
        float hacc[8] = {0.f, 0.f, 0.f, 0.f, 0.f, 0.f, 0.f, 0.f};
        float se[8]   = {0.f, 0.f, 0.f, 0.f, 0.f, 0.f, 0.f, 0.f};

        if (wdeg > 0) {
            uint4 qr = *(const uint4*)&qk2_s[ln][head * 64 + l8 * 8];
            float qk0 = bfu_lo(qr.x), qk1 = bfu_hi(qr.x);
            float qk2f = bfu_lo(qr.y), qk3 = bfu_hi(qr.y);
            float qk4 = bfu_lo(qr.z), qk5 = bfu_hi(qr.z);
            float qk6 = bfu_lo(qr.w), qk7 = bfu_hi(qr.w);
            float4 qcA = *(const float4*)&qc_s[ln][head * 8];
            float4 qcB = *(const float4*)&qc_s[ln][head * 8 + 4];
            float qb = qc_s[ln][16 + head];

            bool dpos = (deg > 0);
            int dclamp = dpos ? (deg - 1) : 0;

            int offL = *(const int*)(erec + (size_t)(dpos ? (start + min(l16, dclamp)) : 0) * 32);
            int o0 = __shfl(offL, grp * 16);
            uint4 ca = *(const uint4*)(hbb + (size_t)(unsigned)o0 + l8 * 16);
            int gi0 = dpos ? start : 0;
            uint4 ev = *(const uint4*)(erec + (size_t)gi0 * 32 + 16);

            for (int it = 0; it < wdeg; ++it) {
                int itn = it + 1;
                if ((itn & 15) == 0)
                    offL = *(const int*)(erec +
                            (size_t)(dpos ? (start + min(itn + l16, dclamp)) : 0) * 32);
                int itc = min(itn, wdeg - 1);
                int on = __shfl(offL, grp * 16 + (itc & 15));
                uint4 na = *(const uint4*)(hbb + (size_t)(unsigned)on + l8 * 16);
                int gin = dpos ? (start + min(itc, dclamp)) : 0;
                uint4 fv = *(const uint4*)(erec + (size_t)gin * 32 + 16);

                float h0 = bfu_lo(ca.x), h1 = bfu_hi(ca.x);
                float h2 = bfu_lo(ca.y), h3 = bfu_hi(ca.y);
                float h4 = bfu_lo(ca.z), h5 = bfu_hi(ca.z);
                float h6 = bfu_lo(ca.w), h7 = bfu_hi(ca.w);
                float dt = qk0 * h0 + qk1 * h1 + qk2f * h2 + qk3 * h3
                         + qk4 * h4 + qk5 * h5 + qk6 * h6 + qk7 * h7;
                dt += __shfl_xor(dt, 1);
                dt += __shfl_xor(dt, 2);
                dt += __shfl_xor(dt, 4);
                float ex0 = bfu_lo(ev.x), ex1 = bfu_hi(ev.x);
                float ex2 = bfu_lo(ev.y), ex3 = bfu_hi(ev.y);
                float ex4 = bfu_lo(ev.z), ex5 = bfu_hi(ev.z);
                float ex6 = bfu_lo(ev.w), ex7 = bfu_hi(ev.w);
                float s0 = dt
                         + qcA.x * ex0 + qcA.y * ex1 + qcA.z * ex2 + qcA.w * ex3
                         + qcB.x * ex4 + qcB.y * ex5 + qcB.z * ex6 + qcB.w * ex7
                         + qb;
                float p = (it < deg) ? __expf(fmaxf(s0, -60.f)) : 0.f;
                lsum += p;
                hacc[0] += p * h0; hacc[1] += p * h1;
                hacc[2] += p * h2; hacc[3] += p * h3;
                hacc[4] += p * h4; hacc[5] += p * h5;
                hacc[6] += p * h6; hacc[7] += p * h7;
                se[0] += p * ex0; se[1] += p * ex1; se[2] += p * ex2; se[3] += p * ex3;
                se[4] += p * ex4; se[5] += p * ex5; se[6] += p * ex6; se[7] += p * ex7;
                ca = na; ev = fv;
            }
        }

        float inv = (deg > 0) ? (0.5f / lsum) : 0.f;   // 0.5 = head mean
#pragma unroll
        for (int j2 = 0; j2 < 8; ++j2)
            ha_s[ln][head * 64 + l8 * 8 + j2] = f2bf(hacc[j2] * inv);
        if (l8 == 0) {
#pragma unroll
            for (int m = 0; m < 8; ++m) sen_s[ln][head * 8 + m] = se[m] * inv;
            if (head == 0) dw_s[ln] = (deg > 0) ? 1.f : 0.f;
        }
    }
    __syncthreads();

    // ---- Phase 2: V-apply MFMA + ep-compose + cst + skip -> outbuf + BN partials ----
    {
        int quad = lane >> 4, nn16 = lane & 15;
        int ct = wid & 3, g = wid >> 2;
        float4v c = {0.f, 0.f, 0.f, 0.f};
#pragma unroll
        for (int kc = 0; kc < 4; ++kc) {
            short8 a = *(const short8*)&ha_s[g * 16 + nn16][kc * 32 + quad * 8];
            short8 b = *(const short8*)(wv_arr + kc * 2048 + ct * 512 + lane * 8);
            c = __builtin_amdgcn_mfma_f32_16x16x32_bf16(a, b, c, 0, 0, 0);
        }
        int col = ct * 16 + nn16;
        float sa = 0.f, sq = 0.f;
#pragma unroll
        for (int r = 0; r < 4; ++r) {
            int ln2 = g * 16 + quad * 4 + r;
            int nr = n0 + ln2;
            const float* sp = sen_s[ln2];
            float ep = 0.f;
#pragma unroll
            for (int hh = 0; hh < 2; ++hh)
#pragma unroll
                for (int d = 0; d < 8; ++d)
                    ep += sp[hh * 8 + d] * Wc_s[d * 128 + hh * 64 + col];
            if (nr < N) {
                float val = c[r] + ep + dw_s[ln2] * cst_s[col] + skip_s[ln2][col];
                outbuf[(size_t)nr * 64 + col] = val;
                sa += val;
                sq += val * val;
            }
        }
        sa += __shfl_xor(sa, 16); sa += __shfl_xor(sa, 32);
        sq += __shfl_xor(sq, 16); sq += __shfl_xor(sq, 32);
        if (quad == 0) { ps[g][col] = sa; ps[g][64 + col] = sq; }
    }
    __syncthreads();
    if (t < 128) part[(size_t)blockIdx.x * 128 + t] = ps[0][t] + ps[1][t];
}

// ---------------- BN reduce + BN apply kernels ----------------

__global__ __launch_bounds__(256) void bnreduce_kernel(const float* __restrict__ part,
                                                       float* __restrict__ bnsums, int nb) {
    int s = blockIdx.x;  // 0..127
    int t = threadIdx.x;
    float a = 0.f;
    for (int b = t; b < nb; b += 256) a += part[(size_t)b * 128 + s];
    __shared__ float sh[256];
    sh[t] = a;
    __syncthreads();
    for (int d = 128; d; d >>= 1) {
        if (t < d) sh[t] += sh[t + d];
        __syncthreads();
    }
    if (t == 0) bnsums[s] = sh[0];
}

// inter-layer BN apply: h update + h_bf for next layer's gather
__global__ __launch_bounds__(256) void bnh_kernel(
    const float* __restrict__ outbuf, const float* __restrict__ bnsums,
    const float* __restrict__ gamma, const float* __restrict__ beta,
    float* __restrict__ h, ushort_t* __restrict__ h_bf, int N) {
    int idx = blockIdx.x * 256 + threadIdx.x;
    if (idx >= N * 64) return;
    int c = idx & 63;
    float invN = 1.f / (float)N;
    float mean = bnsums[c] * invN;
    float var = bnsums[64 + c] * invN - mean * mean;
    float scale = gamma[c] * rsqrtf(var + 1e-5f);
    float shift = beta[c] - mean * scale;
    float o = outbuf[idx] * scale + shift;
    o = (o > 0.f) ? o : 0.01f * o;
    float hn = h[idx] + o;
    h[idx] = hn;
    h_bf[idx] = f2bf(hn);
}

// final BN apply with gate
__global__ __launch_bounds__(256) void bnapply_kernel(
    const float* __restrict__ outbuf, const float* __restrict__ bnsums,
    const float* __restrict__ gamma, const float* __restrict__ beta,
    const float* __restrict__ gate_W, const float* __restrict__ gate_b,
    float* __restrict__ h, float* __restrict__ gatebuf, int N) {
    int idx = blockIdx.x * 256 + threadIdx.x;
    if (idx >= N * 64) return;
    int c = idx & 63, n = idx >> 6;
    float invN = 1.f / (float)N;
    float mean = bnsums[c] * invN;
    float var = bnsums[64 + c] * invN - mean * mean;
    float scale = gamma[c] * rsqrtf(var + 1e-5f);
    float shift = beta[c] - mean * scale;
    float o = outbuf[idx] * scale + shift;
    o = (o > 0.f) ? o : 0.01f * o;
    float hn = h[idx] + o;
    h[idx] = hn;
    float g = hn * gate_W[c];
#pragma unroll
    for (int off = 32; off; off >>= 1) g += __shfl_xor(g, off);
    if (c == 0) gatebuf[n] = g + gate_b[0];
}

// ---------------- pooling (max fused into acc) ----------------

__global__ __launch_bounds__(256) void pool_acc_kernel(
    const float* __restrict__ h, const float* __restrict__ gatebuf,
    const int* __restrict__ batch,
    float* __restrict__ pacc, float* __restrict__ pden, int N) {
    int b = blockIdx.x >> 3, chunk = blockIdx.x & 7;
    int lo = 0, hi = N;
    while (lo < hi) { int mid = (lo + hi) >> 1; if (batch[mid] < b) lo = mid + 1; else hi = mid; }
    int start = lo;
    lo = start; hi = N;
    while (lo < hi) { int mid = (lo + hi) >> 1; if (batch[mid] <= b) lo = mid + 1; else hi = mid; }
    int end = lo;
    int t = threadIdx.x, lane = t & 63, wid = t >> 6;
    __shared__ float sm[4];
    float mx = -1e30f;
    for (int n = start + t; n < end; n += 256) mx = fmaxf(mx, gatebuf[n]);
#pragma unroll
    for (int off = 32; off; off >>= 1) mx = fmaxf(mx, __shfl_xor(mx, off));
    if (lane == 0) sm[wid] = mx;
    __syncthreads();
    float mb = fmaxf(fmaxf(sm[0], sm[1]), fmaxf(sm[2], sm[3]));
    int gwid = chunk * 4 + wid;
    float acc = 0.f, den = 0.f;
    for (int n = start + gwid; n < end; n += 32) {
        float ge = __expf(gatebuf[n] - mb);
        acc += ge * h[(size_t)n * 64 + lane];
        den += ge;
    }
    __shared__ float sacc[4][64];
    __shared__ float sden[4];
    sacc[wid][lane] = acc;
    if (lane == 0) sden[wid] = den;
    __syncthreads();
    if (wid == 0) {
        pacc[(size_t)blockIdx.x * 64 + lane] =
            sacc[0][lane] + sacc[1][lane] + sacc[2][lane] + sacc[3][lane];
        if (lane == 0) pden[blockIdx.x] = sden[0] + sden[1] + sden[2] + sden[3];
    }
}

__global__ void pool_fin_kernel(const float* __restrict__ pacc, const float* __restrict__ pden,
                                const float* __restrict__ out_W, const float* __restrict__ out_b,
                                float* __restrict__ out) {
    int b = blockIdx.x, c = threadIdx.x;
    float pc = 0.f, dv = 0.f;
#pragma unroll
    for (int j = 0; j < 8; ++j) {
        pc += pacc[(size_t)(b * 8 + j) * 64 + c];
        dv += pden[b * 8 + j];
    }
    float s = pc * out_W[c];
#pragma unroll
    for (int off = 32; off; off >>= 1) s += __shfl_xor(s, off);
    if (c == 0) {
        if (dv <= 0.f) dv = 1.f;
        float v = s / dv + out_b[0];
        out[b] = 1.f / (1.f + __expf(-v));
    }
}

// ---------------- host ----------------

extern "C" void kernel_launch(void* const* d_in, const int* in_sizes, int n_in,
                              void* d_out, int out_size, void* d_ws, size_t ws_size,
                              hipStream_t stream) {
    const float* x         = (const float*)d_in[0];
    const float* edge_attr = (const float*)d_in[1];
    const int*   edge_src  = (const int*)d_in[2];
    const int*   edge_dst  = (const int*)d_in[3];
    const int*   batch     = (const int*)d_in[4];
    const float* node_W    = (const float*)d_in[5];
    const float* node_b    = (const float*)d_in[6];
    const float* edge_W    = (const float*)d_in[7];
    const float* edge_b    = (const float*)d_in[8];
    const float* Wq        = (const float*)d_in[9];
    const float* bq        = (const float*)d_in[10];
    const float* Wk        = (const float*)d_in[11];
    const float* bk        = (const float*)d_in[12];
    const float* Wv        = (const float*)d_in[13];
    const float* bv        = (const float*)d_in[14];
    const float* We        = (const float*)d_in[15];
    const float* be        = (const float*)d_in[16];
    const float* Wskip     = (const float*)d_in[17];
    const float* bskip     = (const float*)d_in[18];
    const float* gamma     = (const float*)d_in[19];
    const float* beta      = (const float*)d_in[20];
    const float* gate_W    = (const float*)d_in[21];
    const float* gate_b    = (const float*)d_in[22];
    const float* out_W     = (const float*)d_in[23];
    const float* out_b     = (const float*)d_in[24];
    float* out = (float*)d_out;

    const int N = in_sizes[0] / 16;
    const int E = in_sizes[2];
    const int nbv = (N + 31) / 32;   // layer blocks: 32 nodes per block

    char* ws = (char*)d_ws;
    size_t off = 0;
    auto alloc = [&](size_t bytes) {
        size_t o = off;
        off += (bytes + 255) & ~(size_t)255;
        return o;
    };
    float*    h        = (float*)(ws + alloc((size_t)N * 64 * 4));
    ushort_t* h_bf     = (ushort_t*)(ws + alloc((size_t)N * 64 * 2));
    float*    outbuf   = (float*)(ws + alloc((size_t)N * 64 * 4));
    int*      rowptr   = (int*)(ws + alloc((size_t)(N + 1) * 4));
    int*      cursor   = (int*)(ws + alloc((size_t)N * 4));
    int*      counts   = (int*)(ws + alloc((size_t)N * 4));
    int*      bsums    = (int*)(ws + alloc(1024));
    char*     erec     = (char*)(ws + alloc((size_t)E * 32));
    float*    Wc       = (float*)(ws + alloc(2 * 1024 * 4));
    float*    bcb      = (float*)(ws + alloc(2 * 128 * 4));
    ushort_t* Wall_arr = (ushort_t*)(ws + alloc(2 * 14336 * 2));
    float*    Wall_b   = (float*)(ws + alloc(2 * 224 * 4));
    ushort_t* wv_arr   = (ushort_t*)(ws + alloc(2 * 8192 * 2));
    float*    cst      = (float*)(ws + alloc(2 * 64 * 4));
    float*    bnsums   = (float*)(ws + alloc(128 * 4));
    float*    gatebuf  = (float*)(ws + alloc((size_t)N * 4));
    float*    part     = (float*)(ws + alloc((size_t)nbv * 128 * 4));
    float*    pacc     = (float*)(ws + alloc((size_t)512 * 64 * 4));
    float*    pden     = (float*)(ws + alloc(512 * 4));
    if (off > ws_size) return;

    int O0 = (N * 64 + 255) / 256;
    int O1 = O0 + (N + 255) / 256;
    int O2 = O1 + 9;
    int O3 = O2 + 178;   // 2*14336 + 2*224 + 2*8192 = 45504 -> 178 blocks
    setup_kernel<<<O3, 256, 0, stream>>>(
        x, node_W, node_b, edge_W, edge_b, We, be, Wq, bq, Wk, bk, Wv, bv, Wskip, bskip,
        h, h_bf, counts, Wc, bcb, Wall_arr, Wall_b, wv_arr, O0, O1, O2, N);
    combine2_kernel<<<10, 256, 0, stream>>>(Wq, bq, bk, bv, Wc, bcb, Wall_arr, Wall_b, cst);

    csr_count_kernel<<<(E + 255) / 256, 256, 0, stream>>>(edge_dst, counts, E);
    int nb = (N + 255) / 256;
    scan1_kernel<<<nb, 256, 0, stream>>>(counts, rowptr, bsums, N);
    scan3_kernel<<<nb, 256, 0, stream>>>(rowptr, bsums, cursor, N, E, nb);
    csr_fill_kernel<<<(E + 255) / 256, 256, 0, stream>>>(edge_dst, edge_src, edge_attr,
                                                         cursor, erec, E);

    // layer 0
    layer_kernel<<<nbv, 512, 0, stream>>>(h_bf, erec, rowptr,
                                          Wall_arr, Wall_b, wv_arr, Wc, cst,
                                          outbuf, part, N);
    bnreduce_kernel<<<128, 256, 0, stream>>>(part, bnsums, nbv);
    bnh_kernel<<<(N * 64 + 255) / 256, 256, 0, stream>>>(
        outbuf, bnsums, gamma, beta, h, h_bf, N);

    // layer 1
    layer_kernel<<<nbv, 512, 0, stream>>>(h_bf, erec, rowptr,
                                          Wall_arr + 14336, Wall_b + 224, wv_arr + 8192,
                                          Wc + 1024, cst + 64,
                                          outbuf, part, N);
    bnreduce_kernel<<<128, 256, 0, stream>>>(part, bnsums, nbv);
    bnapply_kernel<<<(N * 64 + 255) / 256, 256, 0, stream>>>(
        outbuf, bnsums, gamma + 64, beta + 64, gate_W, gate_b, h, gatebuf, N);

    pool_acc_kernel<<<512, 256, 0, stream>>>(h, gatebuf, batch, pacc, pden, N);
    pool_fin_kernel<<<64, 64, 0, stream>>>(pacc, pden, out_W, out_b, out);
}